// Round 1
// baseline (794.002 us; speedup 1.0000x reference)
//
#include <hip/hip_runtime.h>

// Problem constants (validated against in_sizes at runtime where cheap)
#define D_IN  128
#define D_HID 256
#define D_OUT 128

constexpr int BM = 128;
constexpr int BN = 128;

// ---------------------------------------------------------------------------
// CSR construction
// ---------------------------------------------------------------------------
__global__ __launch_bounds__(256) void count_edges_kernel(
    const int* __restrict__ src, const int* __restrict__ dst,
    int* __restrict__ cntU, int* __restrict__ cntI, int E)
{
  int e = blockIdx.x * 256 + threadIdx.x;
  if (e < E) {
    atomicAdd(&cntI[dst[e]], 1);
    atomicAdd(&cntU[src[e]], 1);
  }
}

// Single-block exclusive scan, 1024 threads, 8 elements/thread/chunk.
__global__ __launch_bounds__(1024) void exscan_kernel(
    const int* __restrict__ cnt, int* __restrict__ rowptr,
    int* __restrict__ cursor, int n)
{
  __shared__ int wsum[16];
  __shared__ int s_carry;
  const int tid = threadIdx.x;
  const int lane = tid & 63, wid = tid >> 6;
  if (tid == 0) s_carry = 0;
  __syncthreads();
  for (int base = 0; base < n; base += 8192) {
    int idx0 = base + tid * 8;
    int v[8], pre[8];
    int s = 0;
    #pragma unroll
    for (int j = 0; j < 8; ++j) {
      int i = idx0 + j;
      v[j] = (i < n) ? cnt[i] : 0;
      pre[j] = s;
      s += v[j];
    }
    // wave-inclusive scan of per-thread sums
    int ws = s;
    #pragma unroll
    for (int off = 1; off < 64; off <<= 1) {
      int t = __shfl_up(ws, off);
      if (lane >= off) ws += t;
    }
    if (lane == 63) wsum[wid] = ws;
    __syncthreads();
    int carry = s_carry;
    int woff = 0;
    #pragma unroll
    for (int w = 0; w < 16; ++w)
      if (w < wid) woff += wsum[w];
    int texcl = carry + woff + (ws - s);
    #pragma unroll
    for (int j = 0; j < 8; ++j) {
      int i = idx0 + j;
      if (i < n) { rowptr[i] = texcl + pre[j]; cursor[i] = texcl + pre[j]; }
    }
    __syncthreads();
    if (tid == 1023) s_carry = carry + woff + ws;
    __syncthreads();
  }
  if (tid == 0) rowptr[n] = s_carry;
}

__global__ __launch_bounds__(256) void fill_edges_kernel(
    const int* __restrict__ src, const int* __restrict__ dst,
    int* __restrict__ curU, int* __restrict__ curI,
    int* __restrict__ colU, int* __restrict__ colI, int E)
{
  int e = blockIdx.x * 256 + threadIdx.x;
  if (e < E) {
    int s = src[e], d = dst[e];
    int p = atomicAdd(&curI[d], 1); colI[p] = s;
    int q = atomicAdd(&curU[s], 1); colU[q] = d;
  }
}

// ---------------------------------------------------------------------------
// Mean aggregation: one 64-lane wave per destination node.
// D=128: float2/lane, D=256: float4/lane (full row per edge, coalesced).
// ---------------------------------------------------------------------------
template <int D>
__global__ __launch_bounds__(256) void agg_mean_kernel(
    const float* __restrict__ x, const int* __restrict__ rowptr,
    const int* __restrict__ col, float* __restrict__ out, int n)
{
  int gid = blockIdx.x * 256 + threadIdx.x;
  int node = gid >> 6, lane = gid & 63;
  if (node >= n) return;
  int beg = rowptr[node], end = rowptr[node + 1];
  int deg = end - beg;
  float sc = 1.0f / (float)(deg > 0 ? deg : 1);
  if (D == 128) {
    float ax = 0.f, ay = 0.f;
    for (int e = beg; e < end; ++e) {
      int s = col[e];
      float2 vv = *(const float2*)(x + (size_t)s * 128 + lane * 2);
      ax += vv.x; ay += vv.y;
    }
    float2 r; r.x = ax * sc; r.y = ay * sc;
    *(float2*)(out + (size_t)node * 128 + lane * 2) = r;
  } else {
    float a0 = 0.f, a1 = 0.f, a2 = 0.f, a3 = 0.f;
    for (int e = beg; e < end; ++e) {
      int s = col[e];
      float4 vv = *(const float4*)(x + (size_t)s * 256 + lane * 4);
      a0 += vv.x; a1 += vv.y; a2 += vv.z; a3 += vv.w;
    }
    float4 r; r.x = a0 * sc; r.y = a1 * sc; r.z = a2 * sc; r.w = a3 * sc;
    *(float4*)(out + (size_t)node * 256 + lane * 4) = r;
  }
}

// ---------------------------------------------------------------------------
// Fused dual GEMM: C[M,N] = A1[M,K]@W1[K,N] + A2[M,K]@W2[K,N] + b, opt. relu
// (a single GEMM with K' = 2K, alternating source per K-chunk)
// 128x128 tile, 256 threads, 8x8 micro-tile split 2x(4+4) for bank safety.
// ---------------------------------------------------------------------------
template <int K, int N, bool RELU>
__global__ __launch_bounds__(256) void gemm_dual_kernel(
    const float* __restrict__ A1, const float* __restrict__ W1,
    const float* __restrict__ A2, const float* __restrict__ W2,
    const float* __restrict__ bias, float* __restrict__ C, int M)
{
  __shared__ float As[16][BM];
  __shared__ float Ws[16][BN];
  const int tid = threadIdx.x;
  const int tx = tid & 15, ty = tid >> 4;
  const int m0 = blockIdx.x * BM;
  const int n0 = blockIdx.y * BN;

  float acc[2][2][4][4]; // [ri][ci][i][j]
  #pragma unroll
  for (int ri = 0; ri < 2; ++ri)
    #pragma unroll
    for (int ci = 0; ci < 2; ++ci)
      #pragma unroll
      for (int i = 0; i < 4; ++i)
        #pragma unroll
        for (int j = 0; j < 4; ++j) acc[ri][ci][i][j] = 0.f;

  constexpr int HC = K / 16;
  for (int c = 0; c < 2 * HC; ++c) {
    const float* __restrict__ A = (c < HC) ? A1 : A2;
    const float* __restrict__ W = (c < HC) ? W1 : W2;
    const int k0 = ((c < HC) ? c : c - HC) * 16;

    // stage A-tile transposed: As[kk][row]
    {
      int r = tid >> 1;
      int kq = (tid & 1) * 8;
      int grow = m0 + r;
      float4 v0 = {0, 0, 0, 0}, v1 = {0, 0, 0, 0};
      if (grow < M) {
        const float* p = A + (size_t)grow * K + k0 + kq;
        v0 = *(const float4*)p;
        v1 = *(const float4*)(p + 4);
      }
      As[kq + 0][r] = v0.x; As[kq + 1][r] = v0.y;
      As[kq + 2][r] = v0.z; As[kq + 3][r] = v0.w;
      As[kq + 4][r] = v1.x; As[kq + 5][r] = v1.y;
      As[kq + 6][r] = v1.z; As[kq + 7][r] = v1.w;
    }
    // stage W-tile: Ws[kk][col]
    {
      int kk = tid >> 4;
      int c0 = (tid & 15) * 8;
      const float* p = W + (size_t)(k0 + kk) * N + n0 + c0;
      float4 w0 = *(const float4*)p;
      float4 w1 = *(const float4*)(p + 4);
      *(float4*)&Ws[kk][c0] = w0;
      *(float4*)&Ws[kk][c0 + 4] = w1;
    }
    __syncthreads();
    #pragma unroll
    for (int kk = 0; kk < 16; ++kk) {
      float av[2][4], wv[2][4];
      *(float4*)&av[0][0] = *(const float4*)&As[kk][ty * 4];
      *(float4*)&av[1][0] = *(const float4*)&As[kk][64 + ty * 4];
      *(float4*)&wv[0][0] = *(const float4*)&Ws[kk][tx * 4];
      *(float4*)&wv[1][0] = *(const float4*)&Ws[kk][64 + tx * 4];
      #pragma unroll
      for (int ri = 0; ri < 2; ++ri)
        #pragma unroll
        for (int ci = 0; ci < 2; ++ci)
          #pragma unroll
          for (int i = 0; i < 4; ++i)
            #pragma unroll
            for (int j = 0; j < 4; ++j)
              acc[ri][ci][i][j] += av[ri][i] * wv[ci][j];
    }
    __syncthreads();
  }

  #pragma unroll
  for (int ri = 0; ri < 2; ++ri)
    #pragma unroll
    for (int i = 0; i < 4; ++i) {
      int row = m0 + ri * 64 + ty * 4 + i;
      if (row < M) {
        #pragma unroll
        for (int ci = 0; ci < 2; ++ci) {
          int colb = n0 + ci * 64 + tx * 4;
          float4 v;
          v.x = acc[ri][ci][i][0] + bias[colb + 0];
          v.y = acc[ri][ci][i][1] + bias[colb + 1];
          v.z = acc[ri][ci][i][2] + bias[colb + 2];
          v.w = acc[ri][ci][i][3] + bias[colb + 3];
          if (RELU) {
            v.x = fmaxf(v.x, 0.f); v.y = fmaxf(v.y, 0.f);
            v.z = fmaxf(v.z, 0.f); v.w = fmaxf(v.w, 0.f);
          }
          *(float4*)&C[(size_t)row * N + colb] = v;
        }
      }
    }
}

// ---------------------------------------------------------------------------
// Decode: out[i] = dot(z_user[ls[i]], z_item[ld[i]]); 16 lanes per label.
// Writes out[0..L) = -dot, out[L..2L) = +dot.
// ---------------------------------------------------------------------------
__global__ __launch_bounds__(256) void decode_kernel(
    const float* __restrict__ zu, const float* __restrict__ zi,
    const int* __restrict__ ls, const int* __restrict__ ld,
    float* __restrict__ out, int L)
{
  int gid = blockIdx.x * 256 + threadIdx.x;
  int li = gid >> 4, lane = gid & 15;
  if (li >= L) return;
  int u = ls[li], v = ld[li];
  const float4* pu = (const float4*)(zu + (size_t)u * 128);
  const float4* pv = (const float4*)(zi + (size_t)v * 128);
  float4 a0 = pu[lane], a1 = pu[lane + 16];
  float4 b0 = pv[lane], b1 = pv[lane + 16];
  float s = a0.x * b0.x + a0.y * b0.y + a0.z * b0.z + a0.w * b0.w
          + a1.x * b1.x + a1.y * b1.y + a1.z * b1.z + a1.w * b1.w;
  #pragma unroll
  for (int m = 8; m >= 1; m >>= 1) s += __shfl_xor(s, m);
  if (lane == 0) {
    out[(size_t)L + li] = s;
    out[li] = -s;
  }
}

// ---------------------------------------------------------------------------
extern "C" void kernel_launch(void* const* d_in, const int* in_sizes, int n_in,
                              void* d_out, int out_size, void* d_ws, size_t ws_size,
                              hipStream_t stream)
{
  const float* x_user = (const float*)d_in[0];
  const float* x_item = (const float*)d_in[1];
  const float* Wl1_ui = (const float*)d_in[2];
  const float* Wr1_ui = (const float*)d_in[3];
  const float* b1_ui  = (const float*)d_in[4];
  const float* Wl1_iu = (const float*)d_in[5];
  const float* Wr1_iu = (const float*)d_in[6];
  const float* b1_iu  = (const float*)d_in[7];
  const float* Wl2_ui = (const float*)d_in[8];
  const float* Wr2_ui = (const float*)d_in[9];
  const float* b2_ui  = (const float*)d_in[10];
  const float* Wl2_iu = (const float*)d_in[11];
  const float* Wr2_iu = (const float*)d_in[12];
  const float* b2_iu  = (const float*)d_in[13];
  const int* src_u = (const int*)d_in[14];
  const int* dst_i = (const int*)d_in[15];
  const int* label_src = (const int*)d_in[16];
  const int* label_dst = (const int*)d_in[17];

  const int nU = in_sizes[0] / D_IN;   // 50000
  const int nI = in_sizes[1] / D_IN;   // 20000
  const int E  = in_sizes[14];         // 300000
  const int L  = in_sizes[16];         // 200000
  float* out = (float*)d_out;

  char* ws = (char*)d_ws;
  size_t off = 0;
  auto alloc = [&](size_t bytes) -> void* {
    void* p = ws + off;
    off = (off + bytes + 255) & ~(size_t)255;
    return p;
  };
  float* aggI = (float*)alloc((size_t)nI * 256 * 4);
  float* aggU = (float*)alloc((size_t)nU * 256 * 4);
  float* hI   = (float*)alloc((size_t)nI * 256 * 4);
  float* hU   = (float*)alloc((size_t)nU * 256 * 4);
  float* zI   = (float*)alloc((size_t)nI * 128 * 4);
  float* zU   = (float*)alloc((size_t)nU * 128 * 4);
  int* cntI = (int*)alloc((size_t)nI * 4);
  int* cntU = (int*)alloc((size_t)nU * 4);
  int* rpI  = (int*)alloc((size_t)(nI + 1) * 4);
  int* rpU  = (int*)alloc((size_t)(nU + 1) * 4);
  int* curI = (int*)alloc((size_t)nI * 4);
  int* curU = (int*)alloc((size_t)nU * 4);
  int* colI = (int*)alloc((size_t)E * 4);
  int* colU = (int*)alloc((size_t)E * 4);
  (void)ws_size; (void)n_in; (void)out_size;

  // CSR build (both directions)
  hipMemsetAsync(cntI, 0, (size_t)nI * 4, stream);
  hipMemsetAsync(cntU, 0, (size_t)nU * 4, stream);
  int eb = (E + 255) / 256;
  count_edges_kernel<<<eb, 256, 0, stream>>>(src_u, dst_i, cntU, cntI, E);
  exscan_kernel<<<1, 1024, 0, stream>>>(cntI, rpI, curI, nI);
  exscan_kernel<<<1, 1024, 0, stream>>>(cntU, rpU, curU, nU);
  fill_edges_kernel<<<eb, 256, 0, stream>>>(src_u, dst_i, curU, curI, colU, colI, E);

  // Layer 1
  agg_mean_kernel<128><<<(nI * 64 + 255) / 256, 256, 0, stream>>>(x_user, rpI, colI, aggI, nI);
  agg_mean_kernel<128><<<(nU * 64 + 255) / 256, 256, 0, stream>>>(x_item, rpU, colU, aggU, nU);
  gemm_dual_kernel<128, 256, true><<<dim3((nI + BM - 1) / BM, 2), 256, 0, stream>>>(
      aggI, Wl1_ui, x_item, Wr1_ui, b1_ui, hI, nI);
  gemm_dual_kernel<128, 256, true><<<dim3((nU + BM - 1) / BM, 2), 256, 0, stream>>>(
      aggU, Wl1_iu, x_user, Wr1_iu, b1_iu, hU, nU);

  // Layer 2
  agg_mean_kernel<256><<<(nI * 64 + 255) / 256, 256, 0, stream>>>(hU, rpI, colI, aggI, nI);
  agg_mean_kernel<256><<<(nU * 64 + 255) / 256, 256, 0, stream>>>(hI, rpU, colU, aggU, nU);
  gemm_dual_kernel<256, 128, false><<<dim3((nI + BM - 1) / BM, 1), 256, 0, stream>>>(
      aggI, Wl2_ui, hI, Wr2_ui, b2_ui, zI, nI);
  gemm_dual_kernel<256, 128, false><<<dim3((nU + BM - 1) / BM, 1), 256, 0, stream>>>(
      aggU, Wl2_iu, hU, Wr2_iu, b2_iu, zU, nU);

  // Decode
  decode_kernel<<<((size_t)L * 16 + 255) / 256, 256, 0, stream>>>(
      zU, zI, label_src, label_dst, out, L);
}

// Round 2
// 552.774 us; speedup vs baseline: 1.4364x; 1.4364x over previous
//
#include <hip/hip_runtime.h>
#include <hip/hip_bf16.h>

#define D_IN  128
#define D_HID 256
#define D_OUT 128

typedef unsigned short u16;
typedef __attribute__((ext_vector_type(8))) __bf16 bf16x8;
typedef __attribute__((ext_vector_type(4))) float f32x4;

__device__ inline u16 f2bf(float x) {
  union { float f; unsigned u; } c; c.f = x;
  unsigned r = (c.u + 0x7fff + ((c.u >> 16) & 1)) >> 16;
  return (u16)r;
}
__device__ inline float bf2f(u16 u) {
  union { unsigned u; float f; } c; c.u = (unsigned)u << 16; return c.f;
}

// ---------------------------------------------------------------------------
// CSR construction
// ---------------------------------------------------------------------------
__global__ __launch_bounds__(256) void count_edges_kernel(
    const int* __restrict__ src, const int* __restrict__ dst,
    int* __restrict__ cntU, int* __restrict__ cntI, int E)
{
  int e = blockIdx.x * 256 + threadIdx.x;
  if (e < E) {
    atomicAdd(&cntI[dst[e]], 1);
    atomicAdd(&cntU[src[e]], 1);
  }
}

__global__ __launch_bounds__(1024) void exscan_kernel(
    const int* __restrict__ cnt, int* __restrict__ rowptr,
    int* __restrict__ cursor, int n)
{
  __shared__ int wsum[16];
  __shared__ int s_carry;
  const int tid = threadIdx.x;
  const int lane = tid & 63, wid = tid >> 6;
  if (tid == 0) s_carry = 0;
  __syncthreads();
  for (int base = 0; base < n; base += 8192) {
    int idx0 = base + tid * 8;
    int v[8], pre[8];
    int s = 0;
    #pragma unroll
    for (int j = 0; j < 8; ++j) {
      int i = idx0 + j;
      v[j] = (i < n) ? cnt[i] : 0;
      pre[j] = s;
      s += v[j];
    }
    int ws = s;
    #pragma unroll
    for (int off = 1; off < 64; off <<= 1) {
      int t = __shfl_up(ws, off);
      if (lane >= off) ws += t;
    }
    if (lane == 63) wsum[wid] = ws;
    __syncthreads();
    int carry = s_carry;
    int woff = 0;
    #pragma unroll
    for (int w = 0; w < 16; ++w)
      if (w < wid) woff += wsum[w];
    int texcl = carry + woff + (ws - s);
    #pragma unroll
    for (int j = 0; j < 8; ++j) {
      int i = idx0 + j;
      if (i < n) { rowptr[i] = texcl + pre[j]; cursor[i] = texcl + pre[j]; }
    }
    __syncthreads();
    if (tid == 1023) s_carry = carry + woff + ws;
    __syncthreads();
  }
  if (tid == 0) rowptr[n] = s_carry;
}

__global__ __launch_bounds__(256) void fill_edges_kernel(
    const int* __restrict__ src, const int* __restrict__ dst,
    int* __restrict__ curU, int* __restrict__ curI,
    int* __restrict__ colU, int* __restrict__ colI, int E)
{
  int e = blockIdx.x * 256 + threadIdx.x;
  if (e < E) {
    int s = src[e], d = dst[e];
    int p = atomicAdd(&curI[d], 1); colI[p] = s;
    int q = atomicAdd(&curU[s], 1); colU[q] = d;
  }
}

// ---------------------------------------------------------------------------
// fp32 -> bf16 conversion (vectorized, grid-stride over float4s)
// ---------------------------------------------------------------------------
__global__ __launch_bounds__(256) void f2bf_kernel(
    const float* __restrict__ in, u16* __restrict__ out, int n4)
{
  int i = blockIdx.x * 256 + threadIdx.x;
  int stride = gridDim.x * 256;
  for (; i < n4; i += stride) {
    float4 v = ((const float4*)in)[i];
    ushort4 r;
    r.x = f2bf(v.x); r.y = f2bf(v.y); r.z = f2bf(v.z); r.w = f2bf(v.w);
    ((ushort4*)out)[i] = r;
  }
}

// Weight convert + transpose: in [K][N] f32 -> out [N][K] bf16. 4 matrices.
template <int K, int N>
__global__ __launch_bounds__(256) void wtrans_kernel(
    const float* __restrict__ i0, const float* __restrict__ i1,
    const float* __restrict__ i2, const float* __restrict__ i3,
    u16* __restrict__ o0, u16* __restrict__ o1,
    u16* __restrict__ o2, u16* __restrict__ o3)
{
  const float* in = (blockIdx.y == 0) ? i0 : (blockIdx.y == 1) ? i1
                  : (blockIdx.y == 2) ? i2 : i3;
  u16* out = (blockIdx.y == 0) ? o0 : (blockIdx.y == 1) ? o1
           : (blockIdx.y == 2) ? o2 : o3;
  int gid = blockIdx.x * 256 + threadIdx.x;
  if (gid >= N * K) return;
  int n = gid / K, k = gid - n * K;
  out[gid] = f2bf(in[(size_t)k * N + n]);
}

// ---------------------------------------------------------------------------
// Mean aggregation over bf16 rows, fp32 accumulate, bf16 out.
// One 64-lane wave per destination node.
// ---------------------------------------------------------------------------
template <int D>
__global__ __launch_bounds__(256) void agg_mean_kernel(
    const u16* __restrict__ x, const int* __restrict__ rowptr,
    const int* __restrict__ col, u16* __restrict__ out, int n)
{
  int gid = blockIdx.x * 256 + threadIdx.x;
  int node = gid >> 6, lane = gid & 63;
  if (node >= n) return;
  int beg = rowptr[node], end = rowptr[node + 1];
  float sc = 1.0f / fmaxf((float)(end - beg), 1.0f);
  if (D == 128) {
    float a0 = 0.f, a1 = 0.f;
    for (int e = beg; e < end; ++e) {
      int s = col[e];
      ushort2 v = *(const ushort2*)(x + (size_t)s * 128 + lane * 2);
      a0 += bf2f(v.x); a1 += bf2f(v.y);
    }
    ushort2 r; r.x = f2bf(a0 * sc); r.y = f2bf(a1 * sc);
    *(ushort2*)(out + (size_t)node * 128 + lane * 2) = r;
  } else {
    float a0 = 0.f, a1 = 0.f, a2 = 0.f, a3 = 0.f;
    for (int e = beg; e < end; ++e) {
      int s = col[e];
      ushort4 v = *(const ushort4*)(x + (size_t)s * 256 + lane * 4);
      a0 += bf2f(v.x); a1 += bf2f(v.y); a2 += bf2f(v.z); a3 += bf2f(v.w);
    }
    ushort4 r;
    r.x = f2bf(a0 * sc); r.y = f2bf(a1 * sc);
    r.z = f2bf(a2 * sc); r.w = f2bf(a3 * sc);
    *(ushort4*)(out + (size_t)node * 256 + lane * 4) = r;
  }
}

// ---------------------------------------------------------------------------
// Fused dual GEMM via bf16 MFMA: C[M,N] = A1@W1 + A2@W2 + b (+relu)
// A row-major [M][K] bf16; W pre-transposed [N][K] bf16.
// 128x128 tile, BK=64, 4 waves in 2x2, each wave 64x64 via 4x4 16x16 frags.
// LDS rows padded to 72 elems (144 B = 9 x 16 B): b128 reads/writes land
// uniformly 8 lanes per 4-bank group (the b128 optimum).
// ---------------------------------------------------------------------------
template <int K, int N, bool RELU, bool OUT_BF16>
__global__ __launch_bounds__(256) void gemm_mfma_kernel(
    const u16* __restrict__ A1, const u16* __restrict__ Wt1,
    const u16* __restrict__ A2, const u16* __restrict__ Wt2,
    const float* __restrict__ bias, void* __restrict__ Cout, int M)
{
  constexpr int BK = 64;
  constexpr int LDT = 72;
  __shared__ u16 As[128 * LDT];
  __shared__ u16 Ws[128 * LDT];
  const int tid = threadIdx.x;
  const int lane = tid & 63, wid = tid >> 6;
  const int wr = wid >> 1, wc = wid & 1;
  const int m0 = blockIdx.x * 128;
  const int n0 = blockIdx.y * 128;
  const int l15 = lane & 15, lg = lane >> 4;

  f32x4 acc[4][4];
  #pragma unroll
  for (int mi = 0; mi < 4; ++mi)
    #pragma unroll
    for (int ni = 0; ni < 4; ++ni) acc[mi][ni] = (f32x4)0.f;

  constexpr int HC = K / BK;
  for (int st = 0; st < 2 * HC; ++st) {
    const u16* Ap; const u16* Wp; int kk;
    if (st < HC) { Ap = A1; Wp = Wt1; kk = st * BK; }
    else         { Ap = A2; Wp = Wt2; kk = (st - HC) * BK; }

    // stage A tile [128][64] into padded LDS
    #pragma unroll
    for (int p = 0; p < 4; ++p) {
      int s = tid + p * 256;
      int r = s >> 3, sl = s & 7;
      int grow = m0 + r;
      uint4 v = {0u, 0u, 0u, 0u};
      if (grow < M) v = *(const uint4*)(Ap + (size_t)grow * K + kk + sl * 8);
      *(uint4*)(&As[r * LDT + sl * 8]) = v;
    }
    // stage W tile [128][64] (N rows always in-bounds; N multiple of 128)
    #pragma unroll
    for (int p = 0; p < 4; ++p) {
      int s = tid + p * 256;
      int r = s >> 3, sl = s & 7;
      *(uint4*)(&Ws[r * LDT + sl * 8]) =
          *(const uint4*)(Wp + (size_t)(n0 + r) * K + kk + sl * 8);
    }
    __syncthreads();

    #pragma unroll
    for (int kh = 0; kh < 2; ++kh) {
      bf16x8 af[4], bf[4];
      #pragma unroll
      for (int mi = 0; mi < 4; ++mi)
        af[mi] = *(const bf16x8*)(&As[(wr * 64 + mi * 16 + l15) * LDT + kh * 32 + lg * 8]);
      #pragma unroll
      for (int ni = 0; ni < 4; ++ni)
        bf[ni] = *(const bf16x8*)(&Ws[(wc * 64 + ni * 16 + l15) * LDT + kh * 32 + lg * 8]);
      #pragma unroll
      for (int mi = 0; mi < 4; ++mi)
        #pragma unroll
        for (int ni = 0; ni < 4; ++ni)
          acc[mi][ni] = __builtin_amdgcn_mfma_f32_16x16x32_bf16(
              af[mi], bf[ni], acc[mi][ni], 0, 0, 0);
    }
    __syncthreads();
  }

  // epilogue: bias (+relu), store fp32 or bf16
  #pragma unroll
  for (int ni = 0; ni < 4; ++ni) {
    int col = n0 + wc * 64 + ni * 16 + l15;
    float bv = bias[col];
    #pragma unroll
    for (int mi = 0; mi < 4; ++mi) {
      int rowb = m0 + wr * 64 + mi * 16 + lg * 4;
      #pragma unroll
      for (int r = 0; r < 4; ++r) {
        int row = rowb + r;
        if (row < M) {
          float v = acc[mi][ni][r] + bv;
          if (RELU) v = fmaxf(v, 0.f);
          if (OUT_BF16) ((u16*)Cout)[(size_t)row * N + col] = f2bf(v);
          else ((float*)Cout)[(size_t)row * N + col] = v;
        }
      }
    }
  }
}

// ---------------------------------------------------------------------------
// Decode: out[i] = dot(z_user[ls[i]], z_item[ld[i]]); 16 lanes per label.
// ---------------------------------------------------------------------------
__global__ __launch_bounds__(256) void decode_kernel(
    const float* __restrict__ zu, const float* __restrict__ zi,
    const int* __restrict__ ls, const int* __restrict__ ld,
    float* __restrict__ out, int L)
{
  int gid = blockIdx.x * 256 + threadIdx.x;
  int li = gid >> 4, lane = gid & 15;
  if (li >= L) return;
  int u = ls[li], v = ld[li];
  const float4* pu = (const float4*)(zu + (size_t)u * 128);
  const float4* pv = (const float4*)(zi + (size_t)v * 128);
  float4 a0 = pu[lane], a1 = pu[lane + 16];
  float4 b0 = pv[lane], b1 = pv[lane + 16];
  float s = a0.x * b0.x + a0.y * b0.y + a0.z * b0.z + a0.w * b0.w
          + a1.x * b1.x + a1.y * b1.y + a1.z * b1.z + a1.w * b1.w;
  #pragma unroll
  for (int m = 8; m >= 1; m >>= 1) s += __shfl_xor(s, m);
  if (lane == 0) {
    out[(size_t)L + li] = s;
    out[li] = -s;
  }
}

// ---------------------------------------------------------------------------
extern "C" void kernel_launch(void* const* d_in, const int* in_sizes, int n_in,
                              void* d_out, int out_size, void* d_ws, size_t ws_size,
                              hipStream_t stream)
{
  const float* x_user = (const float*)d_in[0];
  const float* x_item = (const float*)d_in[1];
  const float* Wl1_ui = (const float*)d_in[2];
  const float* Wr1_ui = (const float*)d_in[3];
  const float* b1_ui  = (const float*)d_in[4];
  const float* Wl1_iu = (const float*)d_in[5];
  const float* Wr1_iu = (const float*)d_in[6];
  const float* b1_iu  = (const float*)d_in[7];
  const float* Wl2_ui = (const float*)d_in[8];
  const float* Wr2_ui = (const float*)d_in[9];
  const float* b2_ui  = (const float*)d_in[10];
  const float* Wl2_iu = (const float*)d_in[11];
  const float* Wr2_iu = (const float*)d_in[12];
  const float* b2_iu  = (const float*)d_in[13];
  const int* src_u = (const int*)d_in[14];
  const int* dst_i = (const int*)d_in[15];
  const int* label_src = (const int*)d_in[16];
  const int* label_dst = (const int*)d_in[17];

  const int nU = in_sizes[0] / D_IN;
  const int nI = in_sizes[1] / D_IN;
  const int E  = in_sizes[14];
  const int L  = in_sizes[16];
  float* out = (float*)d_out;

  char* ws = (char*)d_ws;
  size_t off = 0;
  auto alloc = [&](size_t bytes) -> void* {
    void* p = ws + off;
    off = (off + bytes + 255) & ~(size_t)255;
    return p;
  };
  u16* xU_bf  = (u16*)alloc((size_t)nU * 128 * 2);
  u16* xI_bf  = (u16*)alloc((size_t)nI * 128 * 2);
  u16* wt_l1ui = (u16*)alloc(32768 * 2);
  u16* wt_r1ui = (u16*)alloc(32768 * 2);
  u16* wt_l1iu = (u16*)alloc(32768 * 2);
  u16* wt_r1iu = (u16*)alloc(32768 * 2);
  u16* wt_l2ui = (u16*)alloc(32768 * 2);
  u16* wt_r2ui = (u16*)alloc(32768 * 2);
  u16* wt_l2iu = (u16*)alloc(32768 * 2);
  u16* wt_r2iu = (u16*)alloc(32768 * 2);
  u16* agg1I = (u16*)alloc((size_t)nI * 128 * 2);
  u16* agg1U = (u16*)alloc((size_t)nU * 128 * 2);
  u16* hI    = (u16*)alloc((size_t)nI * 256 * 2);
  u16* hU    = (u16*)alloc((size_t)nU * 256 * 2);
  u16* agg2I = (u16*)alloc((size_t)nI * 256 * 2);
  u16* agg2U = (u16*)alloc((size_t)nU * 256 * 2);
  float* zI  = (float*)alloc((size_t)nI * 128 * 4);
  float* zU  = (float*)alloc((size_t)nU * 128 * 4);
  int* cntI = (int*)alloc((size_t)nI * 4);
  int* cntU = (int*)alloc((size_t)nU * 4);
  int* rpI  = (int*)alloc((size_t)(nI + 1) * 4);
  int* rpU  = (int*)alloc((size_t)(nU + 1) * 4);
  int* curI = (int*)alloc((size_t)nI * 4);
  int* curU = (int*)alloc((size_t)nU * 4);
  int* colI = (int*)alloc((size_t)E * 4);
  int* colU = (int*)alloc((size_t)E * 4);
  (void)ws_size; (void)n_in; (void)out_size;

  // CSR build
  hipMemsetAsync(cntI, 0, (size_t)nI * 4, stream);
  hipMemsetAsync(cntU, 0, (size_t)nU * 4, stream);
  int eb = (E + 255) / 256;
  count_edges_kernel<<<eb, 256, 0, stream>>>(src_u, dst_i, cntU, cntI, E);
  exscan_kernel<<<1, 1024, 0, stream>>>(cntI, rpI, curI, nI);
  exscan_kernel<<<1, 1024, 0, stream>>>(cntU, rpU, curU, nU);
  fill_edges_kernel<<<eb, 256, 0, stream>>>(src_u, dst_i, curU, curI, colU, colI, E);

  // Convert features + weights to bf16 (weights transposed)
  f2bf_kernel<<<2048, 256, 0, stream>>>(x_user, xU_bf, nU * 128 / 4);
  f2bf_kernel<<<1250, 256, 0, stream>>>(x_item, xI_bf, nI * 128 / 4);
  wtrans_kernel<128, 256><<<dim3(128, 4), 256, 0, stream>>>(
      Wl1_ui, Wr1_ui, Wl1_iu, Wr1_iu, wt_l1ui, wt_r1ui, wt_l1iu, wt_r1iu);
  wtrans_kernel<256, 128><<<dim3(128, 4), 256, 0, stream>>>(
      Wl2_ui, Wr2_ui, Wl2_iu, Wr2_iu, wt_l2ui, wt_r2ui, wt_l2iu, wt_r2iu);

  // Layer 1
  agg_mean_kernel<128><<<(nI * 64 + 255) / 256, 256, 0, stream>>>(xU_bf, rpI, colI, agg1I, nI);
  agg_mean_kernel<128><<<(nU * 64 + 255) / 256, 256, 0, stream>>>(xI_bf, rpU, colU, agg1U, nU);
  gemm_mfma_kernel<128, 256, true, true><<<dim3((nI + 127) / 128, 2), 256, 0, stream>>>(
      agg1I, wt_l1ui, xI_bf, wt_r1ui, b1_ui, hI, nI);
  gemm_mfma_kernel<128, 256, true, true><<<dim3((nU + 127) / 128, 2), 256, 0, stream>>>(
      agg1U, wt_l1iu, xU_bf, wt_r1iu, b1_iu, hU, nU);

  // Layer 2
  agg_mean_kernel<256><<<(nI * 64 + 255) / 256, 256, 0, stream>>>(hU, rpI, colI, agg2I, nI);
  agg_mean_kernel<256><<<(nU * 64 + 255) / 256, 256, 0, stream>>>(hI, rpU, colU, agg2U, nU);
  gemm_mfma_kernel<256, 128, false, false><<<dim3((nI + 127) / 128, 1), 256, 0, stream>>>(
      agg2I, wt_l2ui, hI, wt_r2ui, b2_ui, zI, nI);
  gemm_mfma_kernel<256, 128, false, false><<<dim3((nU + 127) / 128, 1), 256, 0, stream>>>(
      agg2U, wt_l2iu, hU, wt_r2iu, b2_iu, zU, nU);

  // Decode
  decode_kernel<<<((size_t)L * 16 + 255) / 256, 256, 0, stream>>>(
      zU, zI, label_src, label_dst, out, L);
}

// Round 6
// 470.842 us; speedup vs baseline: 1.6863x; 1.1740x over previous
//
#include <hip/hip_runtime.h>
#include <hip/hip_bf16.h>

#define D_IN  128
#define D_HID 256
#define D_OUT 128

typedef unsigned short u16;
typedef __attribute__((ext_vector_type(8))) __bf16 bf16x8;
typedef __attribute__((ext_vector_type(4))) float f32x4;

__device__ inline u16 f2bf(float x) {
  union { float f; unsigned u; } c; c.f = x;
  unsigned r = (c.u + 0x7fff + ((c.u >> 16) & 1)) >> 16;
  return (u16)r;
}
__device__ inline float bf2f(u16 u) {
  union { unsigned u; float f; } c; c.u = (unsigned)u << 16; return c.f;
}
__device__ inline float dot2bf(unsigned x, unsigned y) {
  union { unsigned u; float f; } a, b;
  a.u = x << 16; b.u = y << 16;
  float r = a.f * b.f;
  a.u = x & 0xffff0000u; b.u = y & 0xffff0000u;
  return r + a.f * b.f;
}

// ---------------------------------------------------------------------------
// CSR construction: both directions in ONE cnt/rowptr/col set.
//   [0..nI)      = item nodes (dst side),  col slots [0,E)
//   [nI..nI+nU)  = user nodes (src side),  col slots [E,2E)
// ---------------------------------------------------------------------------
__global__ __launch_bounds__(256) void count_edges_kernel(
    const int* __restrict__ src, const int* __restrict__ dst,
    int* __restrict__ cnt, int nI, int E)
{
  int e = blockIdx.x * 256 + threadIdx.x;
  if (e < E) {
    atomicAdd(&cnt[dst[e]], 1);
    atomicAdd(&cnt[nI + src[e]], 1);
  }
}

// Hierarchical scan phase 1: per-block exclusive scan of 2048, emit block sum.
__global__ __launch_bounds__(256) void scan_block_kernel(
    const int* __restrict__ cnt, int* __restrict__ pre,
    int* __restrict__ bsum, int n)
{
  __shared__ int wsum[4];
  const int tid = threadIdx.x, lane = tid & 63, wid = tid >> 6;
  const int i0 = blockIdx.x * 2048 + tid * 8;
  int v[8], p[8], s = 0;
  #pragma unroll
  for (int j = 0; j < 8; ++j) {
    int i = i0 + j;
    v[j] = (i < n) ? cnt[i] : 0;
    p[j] = s; s += v[j];
  }
  int ws = s;
  #pragma unroll
  for (int off = 1; off < 64; off <<= 1) {
    int t = __shfl_up(ws, off);
    if (lane >= off) ws += t;
  }
  if (lane == 63) wsum[wid] = ws;
  __syncthreads();
  int woff = 0;
  #pragma unroll
  for (int w = 0; w < 4; ++w)
    if (w < wid) woff += wsum[w];
  int texcl = woff + ws - s;
  #pragma unroll
  for (int j = 0; j < 8; ++j) {
    int i = i0 + j;
    if (i < n) pre[i] = texcl + p[j];
  }
  if (tid == 255) bsum[blockIdx.x] = woff + ws;
}

// Phase 2: single-block exclusive scan of block sums (nb <= 1024).
__global__ __launch_bounds__(1024) void scan_sums_kernel(
    int* __restrict__ bsum, int nb)
{
  __shared__ int wsum[16];
  const int tid = threadIdx.x, lane = tid & 63, wid = tid >> 6;
  int v = (tid < nb) ? bsum[tid] : 0;
  int ws = v;
  #pragma unroll
  for (int off = 1; off < 64; off <<= 1) {
    int t = __shfl_up(ws, off);
    if (lane >= off) ws += t;
  }
  if (lane == 63) wsum[wid] = ws;
  __syncthreads();
  int woff = 0;
  #pragma unroll
  for (int w = 0; w < 16; ++w)
    if (w < wid) woff += wsum[w];
  if (tid < nb) bsum[tid] = woff + ws - v;
}

// Phase 3: add block offsets; write rowptr and cursor.
__global__ __launch_bounds__(256) void scan_add_kernel(
    const int* __restrict__ pre, const int* __restrict__ bsum,
    int* __restrict__ rowptr, int* __restrict__ cursor, int n, int total)
{
  int i = blockIdx.x * 256 + threadIdx.x;
  if (i < n) {
    int v = pre[i] + bsum[i >> 11];
    rowptr[i] = v;
    cursor[i] = v;
  } else if (i == n) {
    rowptr[n] = total;
  }
}

__global__ __launch_bounds__(256) void fill_edges_kernel(
    const int* __restrict__ src, const int* __restrict__ dst,
    int* __restrict__ cursor, int* __restrict__ col, int nI, int E)
{
  int e = blockIdx.x * 256 + threadIdx.x;
  if (e < E) {
    int s = src[e], d = dst[e];
    int p = atomicAdd(&cursor[d], 1);      col[p] = s;
    int q = atomicAdd(&cursor[nI + s], 1); col[q] = d;
  }
}

// ---------------------------------------------------------------------------
// fp32 -> bf16 conversion (vectorized, grid-stride over float4s)
// ---------------------------------------------------------------------------
__global__ __launch_bounds__(256) void f2bf_kernel(
    const float* __restrict__ in, u16* __restrict__ out, int n4)
{
  int i = blockIdx.x * 256 + threadIdx.x;
  int stride = gridDim.x * 256;
  for (; i < n4; i += stride) {
    float4 v = ((const float4*)in)[i];
    ushort4 r;
    r.x = f2bf(v.x); r.y = f2bf(v.y); r.z = f2bf(v.z); r.w = f2bf(v.w);
    ((ushort4*)out)[i] = r;
  }
}

// Weight convert + transpose: in [K][N] f32 -> out [N][K] bf16. 4 matrices.
template <int K, int N>
__global__ __launch_bounds__(256) void wtrans_kernel(
    const float* __restrict__ i0, const float* __restrict__ i1,
    const float* __restrict__ i2, const float* __restrict__ i3,
    u16* __restrict__ o0, u16* __restrict__ o1,
    u16* __restrict__ o2, u16* __restrict__ o3)
{
  const float* in = (blockIdx.y == 0) ? i0 : (blockIdx.y == 1) ? i1
                  : (blockIdx.y == 2) ? i2 : i3;
  u16* out = (blockIdx.y == 0) ? o0 : (blockIdx.y == 1) ? o1
           : (blockIdx.y == 2) ? o2 : o3;
  int gid = blockIdx.x * 256 + threadIdx.x;
  if (gid >= N * K) return;
  int n = gid / K, k = gid - n * K;
  out[gid] = f2bf(in[(size_t)k * N + n]);
}

// ---------------------------------------------------------------------------
// Mean aggregation over bf16 rows (D=128), fp32 accumulate, bf16 out.
// One 64-lane wave per destination node; each lane owns 2 dims (ushort2).
// ---------------------------------------------------------------------------
__global__ __launch_bounds__(256) void agg_mean_kernel(
    const u16* __restrict__ x, const int* __restrict__ rowptr,
    const int* __restrict__ col, u16* __restrict__ out, int n)
{
  int gid = blockIdx.x * 256 + threadIdx.x;
  int node = gid >> 6, lane = gid & 63;
  if (node >= n) return;
  int beg = rowptr[node], end = rowptr[node + 1];
  float sc = 1.0f / fmaxf((float)(end - beg), 1.0f);
  float a0 = 0.f, a1 = 0.f;
  for (int e = beg; e < end; ++e) {
    int s = col[e];
    ushort2 v = *(const ushort2*)(x + (size_t)s * 128 + lane * 2);
    a0 += bf2f(v.x); a1 += bf2f(v.y);
  }
  ushort2 r; r.x = f2bf(a0 * sc); r.y = f2bf(a1 * sc);
  *(ushort2*)(out + (size_t)node * 128 + lane * 2) = r;
}

// ---------------------------------------------------------------------------
// GEMM via bf16 MFMA: C[M,N] = A1@W1 (+ A2@W2 if DUAL) (+bias) (+add) (+relu)
// A row-major [M][K] bf16; W pre-transposed [N][K] bf16; add bf16 [M][N].
// 128x128 tile, BK=64, 4 waves 2x2, each wave 64x64 via 4x4 16x16x32 frags.
// LDS rows padded to 72 elems (144 B = 9 x 16 B).
// ---------------------------------------------------------------------------
template <int K, int N, bool DUAL, bool RELU, bool HAS_BIAS, bool HAS_ADD, bool OUT_BF16>
__global__ __launch_bounds__(256) void gemm_mfma_kernel(
    const u16* __restrict__ A1, const u16* __restrict__ Wt1,
    const u16* __restrict__ A2, const u16* __restrict__ Wt2,
    const float* __restrict__ bias, const u16* __restrict__ addm,
    void* __restrict__ Cout, int M)
{
  constexpr int BK = 64;
  constexpr int LDT = 72;
  __shared__ u16 As[128 * LDT];
  __shared__ u16 Ws[128 * LDT];
  const int tid = threadIdx.x;
  const int lane = tid & 63, wid = tid >> 6;
  const int wr = wid >> 1, wc = wid & 1;
  const int m0 = blockIdx.x * 128;
  const int n0 = blockIdx.y * 128;
  const int l15 = lane & 15, lg = lane >> 4;

  f32x4 acc[4][4];
  #pragma unroll
  for (int mi = 0; mi < 4; ++mi)
    #pragma unroll
    for (int ni = 0; ni < 4; ++ni) acc[mi][ni] = (f32x4)0.f;

  constexpr int HC = K / BK;
  constexpr int NST = (DUAL ? 2 : 1) * HC;
  for (int st = 0; st < NST; ++st) {
    const u16* Ap; const u16* Wp; int kk;
    if (!DUAL || st < HC) { Ap = A1; Wp = Wt1; kk = st * BK; }
    else                  { Ap = A2; Wp = Wt2; kk = (st - HC) * BK; }

    #pragma unroll
    for (int p = 0; p < 4; ++p) {
      int s = tid + p * 256;
      int r = s >> 3, sl = s & 7;
      int grow = m0 + r;
      uint4 v = {0u, 0u, 0u, 0u};
      if (grow < M) v = *(const uint4*)(Ap + (size_t)grow * K + kk + sl * 8);
      *(uint4*)(&As[r * LDT + sl * 8]) = v;
    }
    #pragma unroll
    for (int p = 0; p < 4; ++p) {
      int s = tid + p * 256;
      int r = s >> 3, sl = s & 7;
      *(uint4*)(&Ws[r * LDT + sl * 8]) =
          *(const uint4*)(Wp + (size_t)(n0 + r) * K + kk + sl * 8);
    }
    __syncthreads();

    #pragma unroll
    for (int kh = 0; kh < 2; ++kh) {
      bf16x8 af[4], bf[4];
      #pragma unroll
      for (int mi = 0; mi < 4; ++mi)
        af[mi] = *(const bf16x8*)(&As[(wr * 64 + mi * 16 + l15) * LDT + kh * 32 + lg * 8]);
      #pragma unroll
      for (int ni = 0; ni < 4; ++ni)
        bf[ni] = *(const bf16x8*)(&Ws[(wc * 64 + ni * 16 + l15) * LDT + kh * 32 + lg * 8]);
      #pragma unroll
      for (int mi = 0; mi < 4; ++mi)
        #pragma unroll
        for (int ni = 0; ni < 4; ++ni)
          acc[mi][ni] = __builtin_amdgcn_mfma_f32_16x16x32_bf16(
              af[mi], bf[ni], acc[mi][ni], 0, 0, 0);
    }
    __syncthreads();
  }

  #pragma unroll
  for (int ni = 0; ni < 4; ++ni) {
    int col = n0 + wc * 64 + ni * 16 + l15;
    float bv = HAS_BIAS ? bias[col] : 0.f;
    #pragma unroll
    for (int mi = 0; mi < 4; ++mi) {
      int rowb = m0 + wr * 64 + mi * 16 + lg * 4;
      #pragma unroll
      for (int r = 0; r < 4; ++r) {
        int row = rowb + r;
        if (row < M) {
          float v = acc[mi][ni][r] + bv;
          if (HAS_ADD) v += bf2f(addm[(size_t)row * N + col]);
          if (RELU) v = fmaxf(v, 0.f);
          if (OUT_BF16) ((u16*)Cout)[(size_t)row * N + col] = f2bf(v);
          else ((float*)Cout)[(size_t)row * N + col] = v;
        }
      }
    }
  }
}

// ---------------------------------------------------------------------------
// Decode over bf16 z: out[i] = dot(zu[ls[i]], zi[ld[i]]); 16 lanes per label,
// one uint4 (8 bf16) per lane per operand.
// ---------------------------------------------------------------------------
__global__ __launch_bounds__(256) void decode_kernel(
    const u16* __restrict__ zu, const u16* __restrict__ zi,
    const int* __restrict__ ls, const int* __restrict__ ld,
    float* __restrict__ out, int L)
{
  int gid = blockIdx.x * 256 + threadIdx.x;
  int li = gid >> 4, lane = gid & 15;
  if (li >= L) return;
  const uint4* pu = (const uint4*)(zu + (size_t)ls[li] * 128);
  const uint4* pv = (const uint4*)(zi + (size_t)ld[li] * 128);
  uint4 a = pu[lane], b = pv[lane];
  float s = dot2bf(a.x, b.x) + dot2bf(a.y, b.y)
          + dot2bf(a.z, b.z) + dot2bf(a.w, b.w);
  #pragma unroll
  for (int m = 8; m >= 1; m >>= 1) s += __shfl_xor(s, m);
  if (lane == 0) {
    out[(size_t)L + li] = s;
    out[li] = -s;
  }
}

// ---------------------------------------------------------------------------
extern "C" void kernel_launch(void* const* d_in, const int* in_sizes, int n_in,
                              void* d_out, int out_size, void* d_ws, size_t ws_size,
                              hipStream_t stream)
{
  const float* x_user = (const float*)d_in[0];
  const float* x_item = (const float*)d_in[1];
  const float* Wl1_ui = (const float*)d_in[2];
  const float* Wr1_ui = (const float*)d_in[3];
  const float* b1_ui  = (const float*)d_in[4];
  const float* Wl1_iu = (const float*)d_in[5];
  const float* Wr1_iu = (const float*)d_in[6];
  const float* b1_iu  = (const float*)d_in[7];
  const float* Wl2_ui = (const float*)d_in[8];
  const float* Wr2_ui = (const float*)d_in[9];
  const float* b2_ui  = (const float*)d_in[10];
  const float* Wl2_iu = (const float*)d_in[11];
  const float* Wr2_iu = (const float*)d_in[12];
  const float* b2_iu  = (const float*)d_in[13];
  const int* src_u = (const int*)d_in[14];
  const int* dst_i = (const int*)d_in[15];
  const int* label_src = (const int*)d_in[16];
  const int* label_dst = (const int*)d_in[17];

  const int nU = in_sizes[0] / D_IN;
  const int nI = in_sizes[1] / D_IN;
  const int E  = in_sizes[14];
  const int L  = in_sizes[16];
  const int nTot = nI + nU;
  float* out = (float*)d_out;

  char* ws = (char*)d_ws;
  size_t off = 0;
  auto alloc = [&](size_t bytes) -> void* {
    void* p = ws + off;
    off = (off + bytes + 255) & ~(size_t)255;
    return p;
  };
  u16* xU_bf  = (u16*)alloc((size_t)nU * 128 * 2);
  u16* xI_bf  = (u16*)alloc((size_t)nI * 128 * 2);
  u16* wt_l1ui = (u16*)alloc(32768 * 2);
  u16* wt_r1ui = (u16*)alloc(32768 * 2);
  u16* wt_l1iu = (u16*)alloc(32768 * 2);
  u16* wt_r1iu = (u16*)alloc(32768 * 2);
  u16* wt_l2ui = (u16*)alloc(32768 * 2);
  u16* wt_r2ui = (u16*)alloc(32768 * 2);
  u16* wt_l2iu = (u16*)alloc(32768 * 2);
  u16* wt_r2iu = (u16*)alloc(32768 * 2);
  u16* agg1I = (u16*)alloc((size_t)nI * 128 * 2);
  u16* agg1U = (u16*)alloc((size_t)nU * 128 * 2);
  u16* hI    = (u16*)alloc((size_t)nI * 256 * 2);
  u16* hU    = (u16*)alloc((size_t)nU * 256 * 2);
  u16* tI    = (u16*)alloc((size_t)nI * 128 * 2);
  u16* tU    = (u16*)alloc((size_t)nU * 128 * 2);
  u16* agg2I = (u16*)alloc((size_t)nI * 128 * 2);
  u16* agg2U = (u16*)alloc((size_t)nU * 128 * 2);
  u16* zI    = (u16*)alloc((size_t)nI * 128 * 2);
  u16* zU    = (u16*)alloc((size_t)nU * 128 * 2);
  int* cnt    = (int*)alloc((size_t)nTot * 4);
  int* pre    = (int*)alloc((size_t)nTot * 4);
  int* bsum   = (int*)alloc(1024 * 4);
  int* rp     = (int*)alloc((size_t)(nTot + 1) * 4);
  int* cursor = (int*)alloc((size_t)nTot * 4);
  int* col    = (int*)alloc((size_t)E * 2 * 4);
  (void)ws_size; (void)n_in; (void)out_size;

  // --- CSR build (fused both directions, hierarchical scan) ---
  hipMemsetAsync(cnt, 0, (size_t)nTot * 4, stream);
  int eb = (E + 255) / 256;
  count_edges_kernel<<<eb, 256, 0, stream>>>(src_u, dst_i, cnt, nI, E);
  int nb = (nTot + 2047) / 2048;
  scan_block_kernel<<<nb, 256, 0, stream>>>(cnt, pre, bsum, nTot);
  scan_sums_kernel<<<1, 1024, 0, stream>>>(bsum, nb);
  scan_add_kernel<<<(nTot + 1 + 255) / 256, 256, 0, stream>>>(
      pre, bsum, rp, cursor, nTot, 2 * E);
  fill_edges_kernel<<<eb, 256, 0, stream>>>(src_u, dst_i, cursor, col, nI, E);
  const int* rpI = rp;
  const int* rpU = rp + nI;

  // --- Convert features + weights to bf16 (weights transposed) ---
  f2bf_kernel<<<2048, 256, 0, stream>>>(x_user, xU_bf, nU * 128 / 4);
  f2bf_kernel<<<1250, 256, 0, stream>>>(x_item, xI_bf, nI * 128 / 4);
  wtrans_kernel<128, 256><<<dim3(128, 4), 256, 0, stream>>>(
      Wl1_ui, Wr1_ui, Wl1_iu, Wr1_iu, wt_l1ui, wt_r1ui, wt_l1iu, wt_r1iu);
  wtrans_kernel<256, 128><<<dim3(128, 4), 256, 0, stream>>>(
      Wl2_ui, Wr2_ui, Wl2_iu, Wr2_iu, wt_l2ui, wt_r2ui, wt_l2iu, wt_r2iu);

  // --- Layer 1: agg(128-dim) then dual GEMM (+relu) ---
  agg_mean_kernel<<<(nI * 64 + 255) / 256, 256, 0, stream>>>(xU_bf, rpI, col, agg1I, nI);
  agg_mean_kernel<<<(nU * 64 + 255) / 256, 256, 0, stream>>>(xI_bf, rpU, col, agg1U, nU);
  gemm_mfma_kernel<128, 256, true, true, true, false, true>
      <<<dim3((nI + 127) / 128, 2), 256, 0, stream>>>(
      agg1I, wt_l1ui, xI_bf, wt_r1ui, b1_ui, nullptr, hI, nI);
  gemm_mfma_kernel<128, 256, true, true, true, false, true>
      <<<dim3((nU + 127) / 128, 2), 256, 0, stream>>>(
      agg1U, wt_l1iu, xU_bf, wt_r1iu, b1_iu, nullptr, hU, nU);

  // --- Layer 2: transform-first (t = h @ Wl2), agg 128-dim, fused z GEMM ---
  gemm_mfma_kernel<256, 128, false, false, false, false, true>
      <<<dim3((nU + 127) / 128, 1), 256, 0, stream>>>(
      hU, wt_l2ui, nullptr, nullptr, nullptr, nullptr, tU, nU);
  gemm_mfma_kernel<256, 128, false, false, false, false, true>
      <<<dim3((nI + 127) / 128, 1), 256, 0, stream>>>(
      hI, wt_l2iu, nullptr, nullptr, nullptr, nullptr, tI, nI);
  agg_mean_kernel<<<(nI * 64 + 255) / 256, 256, 0, stream>>>(tU, rpI, col, agg2I, nI);
  agg_mean_kernel<<<(nU * 64 + 255) / 256, 256, 0, stream>>>(tI, rpU, col, agg2U, nU);
  gemm_mfma_kernel<256, 128, false, false, true, true, true>
      <<<dim3((nI + 127) / 128, 1), 256, 0, stream>>>(
      hI, wt_r2ui, nullptr, nullptr, b2_ui, agg2I, zI, nI);
  gemm_mfma_kernel<256, 128, false, false, true, true, true>
      <<<dim3((nU + 127) / 128, 1), 256, 0, stream>>>(
      hU, wt_r2iu, nullptr, nullptr, b2_iu, agg2U, zU, nU);

  // --- Decode ---
  decode_kernel<<<((size_t)L * 16 + 255) / 256, 256, 0, stream>>>(
      zU, zI, label_src, label_dst, out, L);
}

// Round 7
// 452.695 us; speedup vs baseline: 1.7539x; 1.0401x over previous
//
#include <hip/hip_runtime.h>
#include <hip/hip_bf16.h>

#define D_IN  128
#define D_HID 256
#define D_OUT 128

typedef unsigned short u16;
typedef __attribute__((ext_vector_type(8))) __bf16 bf16x8;
typedef __attribute__((ext_vector_type(4))) float f32x4;

__device__ inline u16 f2bf(float x) {
  union { float f; unsigned u; } c; c.f = x;
  unsigned r = (c.u + 0x7fff + ((c.u >> 16) & 1)) >> 16;
  return (u16)r;
}
__device__ inline float bf2f(u16 u) {
  union { unsigned u; float f; } c; c.u = (unsigned)u << 16; return c.f;
}
__device__ inline float dot2bf(unsigned x, unsigned y) {
  union { unsigned u; float f; } a, b;
  a.u = x << 16; b.u = y << 16;
  float r = a.f * b.f;
  a.u = x & 0xffff0000u; b.u = y & 0xffff0000u;
  return r + a.f * b.f;
}

// ---------------------------------------------------------------------------
// CSR construction: both directions in ONE cnt/rowptr/col set.
//   [0..nI)      = item nodes (dst side),  col slots [0,E)
//   [nI..nI+nU)  = user nodes (src side),  col slots [E,2E)
// ---------------------------------------------------------------------------
__global__ __launch_bounds__(256) void count_edges_kernel(
    const int* __restrict__ src, const int* __restrict__ dst,
    int* __restrict__ cnt, int nI, int E)
{
  int e = blockIdx.x * 256 + threadIdx.x;
  if (e < E) {
    atomicAdd(&cnt[dst[e]], 1);
    atomicAdd(&cnt[nI + src[e]], 1);
  }
}

// Hierarchical scan phase 1: per-block exclusive scan of 2048, emit block sum.
__global__ __launch_bounds__(256) void scan_block_kernel(
    const int* __restrict__ cnt, int* __restrict__ pre,
    int* __restrict__ bsum, int n)
{
  __shared__ int wsum[4];
  const int tid = threadIdx.x, lane = tid & 63, wid = tid >> 6;
  const int i0 = blockIdx.x * 2048 + tid * 8;
  int v[8], p[8], s = 0;
  #pragma unroll
  for (int j = 0; j < 8; ++j) {
    int i = i0 + j;
    v[j] = (i < n) ? cnt[i] : 0;
    p[j] = s; s += v[j];
  }
  int ws = s;
  #pragma unroll
  for (int off = 1; off < 64; off <<= 1) {
    int t = __shfl_up(ws, off);
    if (lane >= off) ws += t;
  }
  if (lane == 63) wsum[wid] = ws;
  __syncthreads();
  int woff = 0;
  #pragma unroll
  for (int w = 0; w < 4; ++w)
    if (w < wid) woff += wsum[w];
  int texcl = woff + ws - s;
  #pragma unroll
  for (int j = 0; j < 8; ++j) {
    int i = i0 + j;
    if (i < n) pre[i] = texcl + p[j];
  }
  if (tid == 255) bsum[blockIdx.x] = woff + ws;
}

// Phase 2: single-block exclusive scan of block sums (nb <= 1024).
__global__ __launch_bounds__(1024) void scan_sums_kernel(
    int* __restrict__ bsum, int nb)
{
  __shared__ int wsum[16];
  const int tid = threadIdx.x, lane = tid & 63, wid = tid >> 6;
  int v = (tid < nb) ? bsum[tid] : 0;
  int ws = v;
  #pragma unroll
  for (int off = 1; off < 64; off <<= 1) {
    int t = __shfl_up(ws, off);
    if (lane >= off) ws += t;
  }
  if (lane == 63) wsum[wid] = ws;
  __syncthreads();
  int woff = 0;
  #pragma unroll
  for (int w = 0; w < 16; ++w)
    if (w < wid) woff += wsum[w];
  if (tid < nb) bsum[tid] = woff + ws - v;
}

// Phase 3: add block offsets; write rowptr and cursor.
__global__ __launch_bounds__(256) void scan_add_kernel(
    const int* __restrict__ pre, const int* __restrict__ bsum,
    int* __restrict__ rowptr, int* __restrict__ cursor, int n, int total)
{
  int i = blockIdx.x * 256 + threadIdx.x;
  if (i < n) {
    int v = pre[i] + bsum[i >> 11];
    rowptr[i] = v;
    cursor[i] = v;
  } else if (i == n) {
    rowptr[n] = total;
  }
}

// Fill with 2-edge ILP (4 independent atomics in flight) and NON-TEMPORAL col
// stores: col lines are falsely shared by random blocks across all 8 XCDs;
// NT stores bypass the per-XCD L2 so partial lines merge at the memory side
// (round-6 profile: 33 MB WRITE_SIZE for a 2.4 MB scatter).
__global__ __launch_bounds__(256) void fill_edges_kernel(
    const int* __restrict__ src, const int* __restrict__ dst,
    int* __restrict__ cursor, int* __restrict__ col, int nI, int E)
{
  int i = blockIdx.x * 256 + threadIdx.x;
  int half = (E + 1) >> 1;
  if (i >= half) return;
  int e2 = i + half;
  bool v2 = e2 < E;
  int s1 = src[i], d1 = dst[i];
  int s2 = v2 ? src[e2] : 0, d2 = v2 ? dst[e2] : 0;
  int p1 = atomicAdd(&cursor[d1], 1);
  int p2 = v2 ? atomicAdd(&cursor[d2], 1) : 0;
  int q1 = atomicAdd(&cursor[nI + s1], 1);
  int q2 = v2 ? atomicAdd(&cursor[nI + s2], 1) : 0;
  __builtin_nontemporal_store(s1, &col[p1]);
  __builtin_nontemporal_store(d1, &col[q1]);
  if (v2) {
    __builtin_nontemporal_store(s2, &col[p2]);
    __builtin_nontemporal_store(d2, &col[q2]);
  }
}

// ---------------------------------------------------------------------------
// fp32 -> bf16 conversion (vectorized, grid-stride over float4s)
// ---------------------------------------------------------------------------
__global__ __launch_bounds__(256) void f2bf_kernel(
    const float* __restrict__ in, u16* __restrict__ out, int n4)
{
  int i = blockIdx.x * 256 + threadIdx.x;
  int stride = gridDim.x * 256;
  for (; i < n4; i += stride) {
    float4 v = ((const float4*)in)[i];
    ushort4 r;
    r.x = f2bf(v.x); r.y = f2bf(v.y); r.z = f2bf(v.z); r.w = f2bf(v.w);
    ((ushort4*)out)[i] = r;
  }
}

// L1 weight convert + transpose: in [128][256] f32 -> out [256][128] bf16. x4.
__global__ __launch_bounds__(256) void wtrans1_kernel(
    const float* __restrict__ i0, const float* __restrict__ i1,
    const float* __restrict__ i2, const float* __restrict__ i3,
    u16* __restrict__ o0, u16* __restrict__ o1,
    u16* __restrict__ o2, u16* __restrict__ o3)
{
  const float* in = (blockIdx.y == 0) ? i0 : (blockIdx.y == 1) ? i1
                  : (blockIdx.y == 2) ? i2 : i3;
  u16* out = (blockIdx.y == 0) ? o0 : (blockIdx.y == 1) ? o1
           : (blockIdx.y == 2) ? o2 : o3;
  int gid = blockIdx.x * 256 + threadIdx.x;
  if (gid >= 256 * 128) return;
  int n = gid >> 7, k = gid & 127;          // out [n][k], n<256, k<128
  out[gid] = f2bf(in[(size_t)k * 256 + n]); // in [k][n]
}

// L2 combined weight: out [256][256] bf16 where out[n][k] =
//   n<128 ? Wt[k][n] : Wp[k][n-128]   (Wt,Wp are [256][128] f32)
__global__ __launch_bounds__(256) void wtrans2_kernel(
    const float* __restrict__ Wt0, const float* __restrict__ Wp0,
    const float* __restrict__ Wt1, const float* __restrict__ Wp1,
    u16* __restrict__ o0, u16* __restrict__ o1)
{
  const float* Wt = blockIdx.y ? Wt1 : Wt0;
  const float* Wp = blockIdx.y ? Wp1 : Wp0;
  u16* out = blockIdx.y ? o1 : o0;
  int gid = blockIdx.x * 256 + threadIdx.x;
  if (gid >= 256 * 256) return;
  int n = gid >> 8, k = gid & 255;
  float v = (n < 128) ? Wt[(size_t)k * 128 + n] : Wp[(size_t)k * 128 + (n - 128)];
  out[gid] = f2bf(v);
}

// ---------------------------------------------------------------------------
// Mean aggregation over bf16 rows (D=128 src stride 128), bf16 out.
// One 64-lane wave per destination node; lane owns 2 dims.
// ---------------------------------------------------------------------------
__global__ __launch_bounds__(256) void agg_mean_kernel(
    const u16* __restrict__ x, const int* __restrict__ rowptr,
    const int* __restrict__ col, u16* __restrict__ out, int n)
{
  int gid = blockIdx.x * 256 + threadIdx.x;
  int node = gid >> 6, lane = gid & 63;
  if (node >= n) return;
  int beg = rowptr[node], end = rowptr[node + 1];
  float sc = 1.0f / fmaxf((float)(end - beg), 1.0f);
  float a0 = 0.f, a1 = 0.f;
  for (int e = beg; e < end; ++e) {
    int s = col[e];
    ushort2 v = *(const ushort2*)(x + (size_t)s * 128 + lane * 2);
    a0 += bf2f(v.x); a1 += bf2f(v.y);
  }
  ushort2 r; r.x = f2bf(a0 * sc); r.y = f2bf(a1 * sc);
  *(ushort2*)(out + (size_t)node * 128 + lane * 2) = r;
}

// ---------------------------------------------------------------------------
// Layer-2 agg + z epilogue: z[node] = mean_{nbr} t[nbr] + p[node] + bias.
// t = cols [0,128) of the src-side [M][256] tp buffer;
// p = cols [128,256) of the dst-side [M][256] tp buffer.
// ---------------------------------------------------------------------------
__global__ __launch_bounds__(256) void agg_z_kernel(
    const u16* __restrict__ t_src, const u16* __restrict__ p_self,
    const float* __restrict__ bias, const int* __restrict__ rowptr,
    const int* __restrict__ col, u16* __restrict__ z, int n)
{
  int gid = blockIdx.x * 256 + threadIdx.x;
  int node = gid >> 6, lane = gid & 63;
  if (node >= n) return;
  int beg = rowptr[node], end = rowptr[node + 1];
  float sc = 1.0f / fmaxf((float)(end - beg), 1.0f);
  float a0 = 0.f, a1 = 0.f;
  for (int e = beg; e < end; ++e) {
    int s = col[e];
    ushort2 v = *(const ushort2*)(t_src + (size_t)s * 256 + lane * 2);
    a0 += bf2f(v.x); a1 += bf2f(v.y);
  }
  ushort2 pv = *(const ushort2*)(p_self + (size_t)node * 256 + 128 + lane * 2);
  float2 bv = *(const float2*)(bias + lane * 2);
  ushort2 r;
  r.x = f2bf(a0 * sc + bf2f(pv.x) + bv.x);
  r.y = f2bf(a1 * sc + bf2f(pv.y) + bv.y);
  *(ushort2*)(z + (size_t)node * 128 + lane * 2) = r;
}

// ---------------------------------------------------------------------------
// GEMM via bf16 MFMA: C[M,N] = A1@W1 (+ A2@W2 if DUAL) (+bias) (+relu)
// A row-major [M][K] bf16; W pre-transposed [N][K] bf16.
// 128x128 tile, BK=64, 4 waves 2x2, each wave 64x64 via 4x4 16x16x32 frags.
// LDS rows padded to 72 elems (144 B = 9 x 16 B).
// ---------------------------------------------------------------------------
template <int K, int N, bool DUAL, bool RELU, bool HAS_BIAS>
__global__ __launch_bounds__(256) void gemm_mfma_kernel(
    const u16* __restrict__ A1, const u16* __restrict__ Wt1,
    const u16* __restrict__ A2, const u16* __restrict__ Wt2,
    const float* __restrict__ bias, u16* __restrict__ Cout, int M)
{
  constexpr int BK = 64;
  constexpr int LDT = 72;
  __shared__ u16 As[128 * LDT];
  __shared__ u16 Ws[128 * LDT];
  const int tid = threadIdx.x;
  const int lane = tid & 63, wid = tid >> 6;
  const int wr = wid >> 1, wc = wid & 1;
  const int m0 = blockIdx.x * 128;
  const int n0 = blockIdx.y * 128;
  const int l15 = lane & 15, lg = lane >> 4;

  f32x4 acc[4][4];
  #pragma unroll
  for (int mi = 0; mi < 4; ++mi)
    #pragma unroll
    for (int ni = 0; ni < 4; ++ni) acc[mi][ni] = (f32x4)0.f;

  constexpr int HC = K / BK;
  constexpr int NST = (DUAL ? 2 : 1) * HC;
  for (int st = 0; st < NST; ++st) {
    const u16* Ap; const u16* Wp; int kk;
    if (!DUAL || st < HC) { Ap = A1; Wp = Wt1; kk = st * BK; }
    else                  { Ap = A2; Wp = Wt2; kk = (st - HC) * BK; }

    #pragma unroll
    for (int p = 0; p < 4; ++p) {
      int s = tid + p * 256;
      int r = s >> 3, sl = s & 7;
      int grow = m0 + r;
      uint4 v = {0u, 0u, 0u, 0u};
      if (grow < M) v = *(const uint4*)(Ap + (size_t)grow * K + kk + sl * 8);
      *(uint4*)(&As[r * LDT + sl * 8]) = v;
    }
    #pragma unroll
    for (int p = 0; p < 4; ++p) {
      int s = tid + p * 256;
      int r = s >> 3, sl = s & 7;
      *(uint4*)(&Ws[r * LDT + sl * 8]) =
          *(const uint4*)(Wp + (size_t)(n0 + r) * K + kk + sl * 8);
    }
    __syncthreads();

    #pragma unroll
    for (int kh = 0; kh < 2; ++kh) {
      bf16x8 af[4], bf[4];
      #pragma unroll
      for (int mi = 0; mi < 4; ++mi)
        af[mi] = *(const bf16x8*)(&As[(wr * 64 + mi * 16 + l15) * LDT + kh * 32 + lg * 8]);
      #pragma unroll
      for (int ni = 0; ni < 4; ++ni)
        bf[ni] = *(const bf16x8*)(&Ws[(wc * 64 + ni * 16 + l15) * LDT + kh * 32 + lg * 8]);
      #pragma unroll
      for (int mi = 0; mi < 4; ++mi)
        #pragma unroll
        for (int ni = 0; ni < 4; ++ni)
          acc[mi][ni] = __builtin_amdgcn_mfma_f32_16x16x32_bf16(
              af[mi], bf[ni], acc[mi][ni], 0, 0, 0);
    }
    __syncthreads();
  }

  #pragma unroll
  for (int ni = 0; ni < 4; ++ni) {
    int col = n0 + wc * 64 + ni * 16 + l15;
    float bv = HAS_BIAS ? bias[col] : 0.f;
    #pragma unroll
    for (int mi = 0; mi < 4; ++mi) {
      int rowb = m0 + wr * 64 + mi * 16 + lg * 4;
      #pragma unroll
      for (int r = 0; r < 4; ++r) {
        int row = rowb + r;
        if (row < M) {
          float v = acc[mi][ni][r] + bv;
          if (RELU) v = fmaxf(v, 0.f);
          Cout[(size_t)row * N + col] = f2bf(v);
        }
      }
    }
  }
}

// ---------------------------------------------------------------------------
// Decode over bf16 z: out[i] = dot(zu[ls[i]], zi[ld[i]]); 16 lanes per label.
// ---------------------------------------------------------------------------
__global__ __launch_bounds__(256) void decode_kernel(
    const u16* __restrict__ zu, const u16* __restrict__ zi,
    const int* __restrict__ ls, const int* __restrict__ ld,
    float* __restrict__ out, int L)
{
  int gid = blockIdx.x * 256 + threadIdx.x;
  int li = gid >> 4, lane = gid & 15;
  if (li >= L) return;
  const uint4* pu = (const uint4*)(zu + (size_t)ls[li] * 128);
  const uint4* pv = (const uint4*)(zi + (size_t)ld[li] * 128);
  uint4 a = pu[lane], b = pv[lane];
  float s = dot2bf(a.x, b.x) + dot2bf(a.y, b.y)
          + dot2bf(a.z, b.z) + dot2bf(a.w, b.w);
  #pragma unroll
  for (int m = 8; m >= 1; m >>= 1) s += __shfl_xor(s, m);
  if (lane == 0) {
    out[(size_t)L + li] = s;
    out[li] = -s;
  }
}

// ---------------------------------------------------------------------------
extern "C" void kernel_launch(void* const* d_in, const int* in_sizes, int n_in,
                              void* d_out, int out_size, void* d_ws, size_t ws_size,
                              hipStream_t stream)
{
  const float* x_user = (const float*)d_in[0];
  const float* x_item = (const float*)d_in[1];
  const float* Wl1_ui = (const float*)d_in[2];
  const float* Wr1_ui = (const float*)d_in[3];
  const float* b1_ui  = (const float*)d_in[4];
  const float* Wl1_iu = (const float*)d_in[5];
  const float* Wr1_iu = (const float*)d_in[6];
  const float* b1_iu  = (const float*)d_in[7];
  const float* Wl2_ui = (const float*)d_in[8];
  const float* Wr2_ui = (const float*)d_in[9];
  const float* b2_ui  = (const float*)d_in[10];
  const float* Wl2_iu = (const float*)d_in[11];
  const float* Wr2_iu = (const float*)d_in[12];
  const float* b2_iu  = (const float*)d_in[13];
  const int* src_u = (const int*)d_in[14];
  const int* dst_i = (const int*)d_in[15];
  const int* label_src = (const int*)d_in[16];
  const int* label_dst = (const int*)d_in[17];

  const int nU = in_sizes[0] / D_IN;
  const int nI = in_sizes[1] / D_IN;
  const int E  = in_sizes[14];
  const int L  = in_sizes[16];
  const int nTot = nI + nU;
  float* out = (float*)d_out;

  char* ws = (char*)d_ws;
  size_t off = 0;
  auto alloc = [&](size_t bytes) -> void* {
    void* p = ws + off;
    off = (off + bytes + 255) & ~(size_t)255;
    return p;
  };
  u16* xU_bf  = (u16*)alloc((size_t)nU * 128 * 2);
  u16* xI_bf  = (u16*)alloc((size_t)nI * 128 * 2);
  u16* wt_l1ui = (u16*)alloc(32768 * 2);
  u16* wt_r1ui = (u16*)alloc(32768 * 2);
  u16* wt_l1iu = (u16*)alloc(32768 * 2);
  u16* wt_r1iu = (u16*)alloc(32768 * 2);
  u16* wt2I    = (u16*)alloc(65536 * 2);   // [tI|pI] weights: (Wl2_iu | Wr2_ui)^T
  u16* wt2U    = (u16*)alloc(65536 * 2);   // [tU|pU] weights: (Wl2_ui | Wr2_iu)^T
  u16* agg1I = (u16*)alloc((size_t)nI * 128 * 2);
  u16* agg1U = (u16*)alloc((size_t)nU * 128 * 2);
  u16* hI    = (u16*)alloc((size_t)nI * 256 * 2);
  u16* hU    = (u16*)alloc((size_t)nU * 256 * 2);
  u16* tpI   = (u16*)alloc((size_t)nI * 256 * 2);  // cols 0-127: tI, 128-255: pI
  u16* tpU   = (u16*)alloc((size_t)nU * 256 * 2);
  u16* zI    = (u16*)alloc((size_t)nI * 128 * 2);
  u16* zU    = (u16*)alloc((size_t)nU * 128 * 2);
  int* cnt    = (int*)alloc((size_t)nTot * 4);
  int* pre    = (int*)alloc((size_t)nTot * 4);
  int* bsum   = (int*)alloc(1024 * 4);
  int* rp     = (int*)alloc((size_t)(nTot + 1) * 4);
  int* cursor = (int*)alloc((size_t)nTot * 4);
  int* col    = (int*)alloc((size_t)E * 2 * 4);
  (void)ws_size; (void)n_in; (void)out_size;

  // --- CSR build (fused both directions, hierarchical scan) ---
  hipMemsetAsync(cnt, 0, (size_t)nTot * 4, stream);
  int eb = (E + 255) / 256;
  count_edges_kernel<<<eb, 256, 0, stream>>>(src_u, dst_i, cnt, nI, E);
  int nb = (nTot + 2047) / 2048;
  scan_block_kernel<<<nb, 256, 0, stream>>>(cnt, pre, bsum, nTot);
  scan_sums_kernel<<<1, 1024, 0, stream>>>(bsum, nb);
  scan_add_kernel<<<(nTot + 1 + 255) / 256, 256, 0, stream>>>(
      pre, bsum, rp, cursor, nTot, 2 * E);
  int half = (E + 1) / 2;
  fill_edges_kernel<<<(half + 255) / 256, 256, 0, stream>>>(
      src_u, dst_i, cursor, col, nI, E);
  const int* rpI = rp;
  const int* rpU = rp + nI;

  // --- Convert features + weights to bf16 ---
  f2bf_kernel<<<2048, 256, 0, stream>>>(x_user, xU_bf, nU * 128 / 4);
  f2bf_kernel<<<1250, 256, 0, stream>>>(x_item, xI_bf, nI * 128 / 4);
  wtrans1_kernel<<<dim3(128, 4), 256, 0, stream>>>(
      Wl1_ui, Wr1_ui, Wl1_iu, Wr1_iu, wt_l1ui, wt_r1ui, wt_l1iu, wt_r1iu);
  wtrans2_kernel<<<dim3(256, 2), 256, 0, stream>>>(
      Wl2_iu, Wr2_ui, Wl2_ui, Wr2_iu, wt2I, wt2U);

  // --- Layer 1: agg(128-dim) then dual GEMM (+bias, +relu) ---
  agg_mean_kernel<<<(nI * 64 + 255) / 256, 256, 0, stream>>>(xU_bf, rpI, col, agg1I, nI);
  agg_mean_kernel<<<(nU * 64 + 255) / 256, 256, 0, stream>>>(xI_bf, rpU, col, agg1U, nU);
  gemm_mfma_kernel<128, 256, true, true, true>
      <<<dim3((nI + 127) / 128, 2), 256, 0, stream>>>(
      agg1I, wt_l1ui, xI_bf, wt_r1ui, b1_ui, hI, nI);
  gemm_mfma_kernel<128, 256, true, true, true>
      <<<dim3((nU + 127) / 128, 2), 256, 0, stream>>>(
      agg1U, wt_l1iu, xU_bf, wt_r1iu, b1_iu, hU, nU);

  // --- Layer 2: fused [t|p] GEMM per side, then agg+z epilogue ---
  gemm_mfma_kernel<256, 256, false, false, false>
      <<<dim3((nI + 127) / 128, 2), 256, 0, stream>>>(
      hI, wt2I, nullptr, nullptr, nullptr, tpI, nI);
  gemm_mfma_kernel<256, 256, false, false, false>
      <<<dim3((nU + 127) / 128, 2), 256, 0, stream>>>(
      hU, wt2U, nullptr, nullptr, nullptr, tpU, nU);
  // zI = mean over item's users of tU + pI + b2_ui
  agg_z_kernel<<<(nI * 64 + 255) / 256, 256, 0, stream>>>(
      tpU, tpI, b2_ui, rpI, col, zI, nI);
  // zU = mean over user's items of tI + pU + b2_iu
  agg_z_kernel<<<(nU * 64 + 255) / 256, 256, 0, stream>>>(
      tpI, tpU, b2_iu, rpU, col, zU, nU);

  // --- Decode ---
  decode_kernel<<<((size_t)L * 16 + 255) / 256, 256, 0, stream>>>(
      zU, zI, label_src, label_dst, out, L);
}

// Round 9
// 375.139 us; speedup vs baseline: 2.1166x; 1.2067x over previous
//
#include <hip/hip_runtime.h>
#include <hip/hip_bf16.h>

#define D_IN  128
#define D_HID 256
#define D_OUT 128

typedef unsigned short u16;
typedef __attribute__((ext_vector_type(8))) __bf16 bf16x8;
typedef __attribute__((ext_vector_type(4))) float f32x4;

__device__ inline u16 f2bf(float x) {
  union { float f; unsigned u; } c; c.f = x;
  unsigned r = (c.u + 0x7fff + ((c.u >> 16) & 1)) >> 16;
  return (u16)r;
}
__device__ inline float bf2f(u16 u) {
  union { unsigned u; float f; } c; c.u = (unsigned)u << 16; return c.f;
}
__device__ inline float dot2bf(unsigned x, unsigned y) {
  union { unsigned u; float f; } a, b;
  a.u = x << 16; b.u = y << 16;
  float r = a.f * b.f;
  a.u = x & 0xffff0000u; b.u = y & 0xffff0000u;
  return r + a.f * b.f;
}

// ---------------------------------------------------------------------------
// CSR construction: both directions in ONE cnt/rowptr/col set.
//   [0..nI)      = item nodes (dst side),  col slots [0,E)
//   [nI..nI+nU)  = user nodes (src side),  col slots [E,2E)
// ---------------------------------------------------------------------------
__global__ __launch_bounds__(256) void count_edges_kernel(
    const int* __restrict__ src, const int* __restrict__ dst,
    int* __restrict__ cnt, int nI, int E)
{
  int e = blockIdx.x * 256 + threadIdx.x;
  if (e < E) {
    atomicAdd(&cnt[dst[e]], 1);
    atomicAdd(&cnt[nI + src[e]], 1);
  }
}

// Hierarchical scan phase 1: per-block exclusive scan of 2048, emit block sum.
__global__ __launch_bounds__(256) void scan_block_kernel(
    const int* __restrict__ cnt, int* __restrict__ pre,
    int* __restrict__ bsum, int n)
{
  __shared__ int wsum[4];
  const int tid = threadIdx.x, lane = tid & 63, wid = tid >> 6;
  const int i0 = blockIdx.x * 2048 + tid * 8;
  int v[8], p[8], s = 0;
  #pragma unroll
  for (int j = 0; j < 8; ++j) {
    int i = i0 + j;
    v[j] = (i < n) ? cnt[i] : 0;
    p[j] = s; s += v[j];
  }
  int ws = s;
  #pragma unroll
  for (int off = 1; off < 64; off <<= 1) {
    int t = __shfl_up(ws, off);
    if (lane >= off) ws += t;
  }
  if (lane == 63) wsum[wid] = ws;
  __syncthreads();
  int woff = 0;
  #pragma unroll
  for (int w = 0; w < 4; ++w)
    if (w < wid) woff += wsum[w];
  int texcl = woff + ws - s;
  #pragma unroll
  for (int j = 0; j < 8; ++j) {
    int i = i0 + j;
    if (i < n) pre[i] = texcl + p[j];
  }
  if (tid == 255) bsum[blockIdx.x] = woff + ws;
}

// Phase 2: single-block exclusive scan of block sums (nb <= 1024).
__global__ __launch_bounds__(1024) void scan_sums_kernel(
    int* __restrict__ bsum, int nb)
{
  __shared__ int wsum[16];
  const int tid = threadIdx.x, lane = tid & 63, wid = tid >> 6;
  int v = (tid < nb) ? bsum[tid] : 0;
  int ws = v;
  #pragma unroll
  for (int off = 1; off < 64; off <<= 1) {
    int t = __shfl_up(ws, off);
    if (lane >= off) ws += t;
  }
  if (lane == 63) wsum[wid] = ws;
  __syncthreads();
  int woff = 0;
  #pragma unroll
  for (int w = 0; w < 16; ++w)
    if (w < wid) woff += wsum[w];
  if (tid < nb) bsum[tid] = woff + ws - v;
}

// Phase 3: add block offsets; write rowptr and cursor.
__global__ __launch_bounds__(256) void scan_add_kernel(
    const int* __restrict__ pre, const int* __restrict__ bsum,
    int* __restrict__ rowptr, int* __restrict__ cursor, int n, int total)
{
  int i = blockIdx.x * 256 + threadIdx.x;
  if (i < n) {
    int v = pre[i] + bsum[i >> 11];
    rowptr[i] = v;
    cursor[i] = v;
  } else if (i == n) {
    rowptr[n] = total;
  }
}

// Fill: 2 edges/thread (4 independent atomics in flight), NORMAL stores
// (round-7 lesson: NT stores bypass L2 write-merging -> WRITE_SIZE 33->42 MB,
// dur 49->69 us; the L2 absorbs some of the random-4B false sharing).
__global__ __launch_bounds__(256) void fill_edges_kernel(
    const int* __restrict__ src, const int* __restrict__ dst,
    int* __restrict__ cursor, int* __restrict__ col, int nI, int E)
{
  int i = blockIdx.x * 256 + threadIdx.x;
  int half = (E + 1) >> 1;
  if (i >= half) return;
  int e2 = i + half;
  bool v2 = e2 < E;
  int s1 = src[i], d1 = dst[i];
  int s2 = v2 ? src[e2] : 0, d2 = v2 ? dst[e2] : 0;
  int p1 = atomicAdd(&cursor[d1], 1);
  int p2 = v2 ? atomicAdd(&cursor[d2], 1) : 0;
  int q1 = atomicAdd(&cursor[nI + s1], 1);
  int q2 = v2 ? atomicAdd(&cursor[nI + s2], 1) : 0;
  col[p1] = s1;
  col[q1] = d1;
  if (v2) {
    col[p2] = s2;
    col[q2] = d2;
  }
}

// ---------------------------------------------------------------------------
// fp32 -> bf16 conversion (vectorized, grid-stride over float4s)
// ---------------------------------------------------------------------------
__global__ __launch_bounds__(256) void f2bf_kernel(
    const float* __restrict__ in, u16* __restrict__ out, int n4)
{
  int i = blockIdx.x * 256 + threadIdx.x;
  int stride = gridDim.x * 256;
  for (; i < n4; i += stride) {
    float4 v = ((const float4*)in)[i];
    ushort4 r;
    r.x = f2bf(v.x); r.y = f2bf(v.y); r.z = f2bf(v.z); r.w = f2bf(v.w);
    ((ushort4*)out)[i] = r;
  }
}

// L1 weight convert + transpose: in [128][256] f32 -> out [256][128] bf16. x4.
__global__ __launch_bounds__(256) void wtrans1_kernel(
    const float* __restrict__ i0, const float* __restrict__ i1,
    const float* __restrict__ i2, const float* __restrict__ i3,
    u16* __restrict__ o0, u16* __restrict__ o1,
    u16* __restrict__ o2, u16* __restrict__ o3)
{
  const float* in = (blockIdx.y == 0) ? i0 : (blockIdx.y == 1) ? i1
                  : (blockIdx.y == 2) ? i2 : i3;
  u16* out = (blockIdx.y == 0) ? o0 : (blockIdx.y == 1) ? o1
           : (blockIdx.y == 2) ? o2 : o3;
  int gid = blockIdx.x * 256 + threadIdx.x;
  if (gid >= 256 * 128) return;
  int n = gid >> 7, k = gid & 127;          // out [n][k]
  out[gid] = f2bf(in[(size_t)k * 256 + n]); // in [k][n]
}

// L2 combined weight: out [256][256] bf16 where out[n][k] =
//   n<128 ? Wt[k][n] : Wp[k][n-128]   (Wt,Wp are [256][128] f32)
__global__ __launch_bounds__(256) void wtrans2_kernel(
    const float* __restrict__ Wt0, const float* __restrict__ Wp0,
    const float* __restrict__ Wt1, const float* __restrict__ Wp1,
    u16* __restrict__ o0, u16* __restrict__ o1)
{
  const float* Wt = blockIdx.y ? Wt1 : Wt0;
  const float* Wp = blockIdx.y ? Wp1 : Wp0;
  u16* out = blockIdx.y ? o1 : o0;
  int gid = blockIdx.x * 256 + threadIdx.x;
  if (gid >= 256 * 256) return;
  int n = gid >> 8, k = gid & 255;
  float v = (n < 128) ? Wt[(size_t)k * 128 + n] : Wp[(size_t)k * 128 + (n - 128)];
  out[gid] = f2bf(v);
}

// ---------------------------------------------------------------------------
// Mean aggregation, MLP-unrolled: one wave per node. Coalesced prefetch of
// up to 64 col indices, __shfl broadcast, 4 independent row loads in flight
// (the serial col->row dependent chain was the latency bottleneck).
// ---------------------------------------------------------------------------
__global__ __launch_bounds__(256) void agg_mean_kernel(
    const u16* __restrict__ x, const int* __restrict__ rowptr,
    const int* __restrict__ col, u16* __restrict__ out, int n)
{
  int gid = blockIdx.x * 256 + threadIdx.x;
  int node = gid >> 6, lane = gid & 63;
  if (node >= n) return;
  int beg = rowptr[node], end = rowptr[node + 1];
  int deg = end - beg;
  float sc = 1.0f / fmaxf((float)deg, 1.0f);
  float a0 = 0.f, a1 = 0.f, b0 = 0.f, b1 = 0.f;
  float c0 = 0.f, c1 = 0.f, d0 = 0.f, d1 = 0.f;
  if (deg <= 64) {
    int cidx = (lane < deg) ? col[beg + lane] : 0;
    int dm1 = deg - 1;
    for (int j = 0; j < deg; j += 4) {
      int i0 = __shfl(cidx, j);
      int i1 = __shfl(cidx, min(j + 1, dm1));
      int i2 = __shfl(cidx, min(j + 2, dm1));
      int i3 = __shfl(cidx, min(j + 3, dm1));
      ushort2 v0 = *(const ushort2*)(x + (size_t)i0 * 128 + lane * 2);
      ushort2 v1 = *(const ushort2*)(x + (size_t)i1 * 128 + lane * 2);
      ushort2 v2 = *(const ushort2*)(x + (size_t)i2 * 128 + lane * 2);
      ushort2 v3 = *(const ushort2*)(x + (size_t)i3 * 128 + lane * 2);
      float m1 = (j + 1 < deg) ? 1.f : 0.f;
      float m2 = (j + 2 < deg) ? 1.f : 0.f;
      float m3 = (j + 3 < deg) ? 1.f : 0.f;
      a0 += bf2f(v0.x);      a1 += bf2f(v0.y);
      b0 += m1 * bf2f(v1.x); b1 += m1 * bf2f(v1.y);
      c0 += m2 * bf2f(v2.x); c1 += m2 * bf2f(v2.y);
      d0 += m3 * bf2f(v3.x); d1 += m3 * bf2f(v3.y);
    }
  } else {
    for (int e = beg; e < end; ++e) {
      int s = col[e];
      ushort2 v = *(const ushort2*)(x + (size_t)s * 128 + lane * 2);
      a0 += bf2f(v.x); a1 += bf2f(v.y);
    }
  }
  float r0 = (a0 + b0) + (c0 + d0);
  float r1 = (a1 + b1) + (c1 + d1);
  ushort2 r; r.x = f2bf(r0 * sc); r.y = f2bf(r1 * sc);
  *(ushort2*)(out + (size_t)node * 128 + lane * 2) = r;
}

// ---------------------------------------------------------------------------
// Layer-2 agg + z epilogue (MLP-unrolled): z = mean_nbr t[nbr] + p[node] + b.
// t = cols [0,128) of src-side [M][256] tp; p = cols [128,256) of dst-side tp.
// ---------------------------------------------------------------------------
__global__ __launch_bounds__(256) void agg_z_kernel(
    const u16* __restrict__ t_src, const u16* __restrict__ p_self,
    const float* __restrict__ bias, const int* __restrict__ rowptr,
    const int* __restrict__ col, u16* __restrict__ z, int n)
{
  int gid = blockIdx.x * 256 + threadIdx.x;
  int node = gid >> 6, lane = gid & 63;
  if (node >= n) return;
  int beg = rowptr[node], end = rowptr[node + 1];
  int deg = end - beg;
  float sc = 1.0f / fmaxf((float)deg, 1.0f);
  float a0 = 0.f, a1 = 0.f, b0 = 0.f, b1 = 0.f;
  float c0 = 0.f, c1 = 0.f, d0 = 0.f, d1 = 0.f;
  if (deg <= 64) {
    int cidx = (lane < deg) ? col[beg + lane] : 0;
    int dm1 = deg - 1;
    for (int j = 0; j < deg; j += 4) {
      int i0 = __shfl(cidx, j);
      int i1 = __shfl(cidx, min(j + 1, dm1));
      int i2 = __shfl(cidx, min(j + 2, dm1));
      int i3 = __shfl(cidx, min(j + 3, dm1));
      ushort2 v0 = *(const ushort2*)(t_src + (size_t)i0 * 256 + lane * 2);
      ushort2 v1 = *(const ushort2*)(t_src + (size_t)i1 * 256 + lane * 2);
      ushort2 v2 = *(const ushort2*)(t_src + (size_t)i2 * 256 + lane * 2);
      ushort2 v3 = *(const ushort2*)(t_src + (size_t)i3 * 256 + lane * 2);
      float m1 = (j + 1 < deg) ? 1.f : 0.f;
      float m2 = (j + 2 < deg) ? 1.f : 0.f;
      float m3 = (j + 3 < deg) ? 1.f : 0.f;
      a0 += bf2f(v0.x);      a1 += bf2f(v0.y);
      b0 += m1 * bf2f(v1.x); b1 += m1 * bf2f(v1.y);
      c0 += m2 * bf2f(v2.x); c1 += m2 * bf2f(v2.y);
      d0 += m3 * bf2f(v3.x); d1 += m3 * bf2f(v3.y);
    }
  } else {
    for (int e = beg; e < end; ++e) {
      int s = col[e];
      ushort2 v = *(const ushort2*)(t_src + (size_t)s * 256 + lane * 2);
      a0 += bf2f(v.x); a1 += bf2f(v.y);
    }
  }
  float r0 = (a0 + b0) + (c0 + d0);
  float r1 = (a1 + b1) + (c1 + d1);
  ushort2 pv = *(const ushort2*)(p_self + (size_t)node * 256 + 128 + lane * 2);
  float2 bv = *(const float2*)(bias + lane * 2);
  ushort2 r;
  r.x = f2bf(r0 * sc + bf2f(pv.x) + bv.x);
  r.y = f2bf(r1 * sc + bf2f(pv.y) + bv.y);
  *(ushort2*)(z + (size_t)node * 128 + lane * 2) = r;
}

// ---------------------------------------------------------------------------
// GEMM via bf16 MFMA: C[M,N] = A1@W1 (+ A2@W2 if DUAL) (+bias) (+relu)
// A row-major [M][K] bf16; W pre-transposed [N][K] bf16.
// 128x128 tile, BK=64, 4 waves 2x2, each wave 64x64 via 4x4 16x16x32 frags.
// LDS rows padded to 72 elems (144 B = 9 x 16 B).
// ---------------------------------------------------------------------------
template <int K, int N, bool DUAL, bool RELU, bool HAS_BIAS>
__global__ __launch_bounds__(256) void gemm_mfma_kernel(
    const u16* __restrict__ A1, const u16* __restrict__ Wt1,
    const u16* __restrict__ A2, const u16* __restrict__ Wt2,
    const float* __restrict__ bias, u16* __restrict__ Cout, int M)
{
  constexpr int BK = 64;
  constexpr int LDT = 72;
  __shared__ u16 As[128 * LDT];
  __shared__ u16 Ws[128 * LDT];
  const int tid = threadIdx.x;
  const int lane = tid & 63, wid = tid >> 6;
  const int wr = wid >> 1, wc = wid & 1;
  const int m0 = blockIdx.x * 128;
  const int n0 = blockIdx.y * 128;
  const int l15 = lane & 15, lg = lane >> 4;

  f32x4 acc[4][4];
  #pragma unroll
  for (int mi = 0; mi < 4; ++mi)
    #pragma unroll
    for (int ni = 0; ni < 4; ++ni) acc[mi][ni] = (f32x4)0.f;

  constexpr int HC = K / BK;
  constexpr int NST = (DUAL ? 2 : 1) * HC;
  for (int st = 0; st < NST; ++st) {
    const u16* Ap; const u16* Wp; int kk;
    if (!DUAL || st < HC) { Ap = A1; Wp = Wt1; kk = st * BK; }
    else                  { Ap = A2; Wp = Wt2; kk = (st - HC) * BK; }

    #pragma unroll
    for (int p = 0; p < 4; ++p) {
      int s = tid + p * 256;
      int r = s >> 3, sl = s & 7;
      int grow = m0 + r;
      uint4 v = {0u, 0u, 0u, 0u};
      if (grow < M) v = *(const uint4*)(Ap + (size_t)grow * K + kk + sl * 8);
      *(uint4*)(&As[r * LDT + sl * 8]) = v;
    }
    #pragma unroll
    for (int p = 0; p < 4; ++p) {
      int s = tid + p * 256;
      int r = s >> 3, sl = s & 7;
      *(uint4*)(&Ws[r * LDT + sl * 8]) =
          *(const uint4*)(Wp + (size_t)(n0 + r) * K + kk + sl * 8);
    }
    __syncthreads();

    #pragma unroll
    for (int kh = 0; kh < 2; ++kh) {
      bf16x8 af[4], bf[4];
      #pragma unroll
      for (int mi = 0; mi < 4; ++mi)
        af[mi] = *(const bf16x8*)(&As[(wr * 64 + mi * 16 + l15) * LDT + kh * 32 + lg * 8]);
      #pragma unroll
      for (int ni = 0; ni < 4; ++ni)
        bf[ni] = *(const bf16x8*)(&Ws[(wc * 64 + ni * 16 + l15) * LDT + kh * 32 + lg * 8]);
      #pragma unroll
      for (int mi = 0; mi < 4; ++mi)
        #pragma unroll
        for (int ni = 0; ni < 4; ++ni)
          acc[mi][ni] = __builtin_amdgcn_mfma_f32_16x16x32_bf16(
              af[mi], bf[ni], acc[mi][ni], 0, 0, 0);
    }
    __syncthreads();
  }

  #pragma unroll
  for (int ni = 0; ni < 4; ++ni) {
    int col = n0 + wc * 64 + ni * 16 + l15;
    float bv = HAS_BIAS ? bias[col] : 0.f;
    #pragma unroll
    for (int mi = 0; mi < 4; ++mi) {
      int rowb = m0 + wr * 64 + mi * 16 + lg * 4;
      #pragma unroll
      for (int r = 0; r < 4; ++r) {
        int row = rowb + r;
        if (row < M) {
          float v = acc[mi][ni][r] + bv;
          if (RELU) v = fmaxf(v, 0.f);
          Cout[(size_t)row * N + col] = f2bf(v);
        }
      }
    }
  }
}

// ---------------------------------------------------------------------------
// Decode over bf16 z: out[i] = dot(zu[ls[i]], zi[ld[i]]); 16 lanes per label.
// ---------------------------------------------------------------------------
__global__ __launch_bounds__(256) void decode_kernel(
    const u16* __restrict__ zu, const u16* __restrict__ zi,
    const int* __restrict__ ls, const int* __restrict__ ld,
    float* __restrict__ out, int L)
{
  int gid = blockIdx.x * 256 + threadIdx.x;
  int li = gid >> 4, lane = gid & 15;
  if (li >= L) return;
  const uint4* pu = (const uint4*)(zu + (size_t)ls[li] * 128);
  const uint4* pv = (const uint4*)(zi + (size_t)ld[li] * 128);
  uint4 a = pu[lane], b = pv[lane];
  float s = dot2bf(a.x, b.x) + dot2bf(a.y, b.y)
          + dot2bf(a.z, b.z) + dot2bf(a.w, b.w);
  #pragma unroll
  for (int m = 8; m >= 1; m >>= 1) s += __shfl_xor(s, m);
  if (lane == 0) {
    out[(size_t)L + li] = s;
    out[li] = -s;
  }
}

// ---------------------------------------------------------------------------
extern "C" void kernel_launch(void* const* d_in, const int* in_sizes, int n_in,
                              void* d_out, int out_size, void* d_ws, size_t ws_size,
                              hipStream_t stream)
{
  const float* x_user = (const float*)d_in[0];
  const float* x_item = (const float*)d_in[1];
  const float* Wl1_ui = (const float*)d_in[2];
  const float* Wr1_ui = (const float*)d_in[3];
  const float* b1_ui  = (const float*)d_in[4];
  const float* Wl1_iu = (const float*)d_in[5];
  const float* Wr1_iu = (const float*)d_in[6];
  const float* b1_iu  = (const float*)d_in[7];
  const float* Wl2_ui = (const float*)d_in[8];
  const float* Wr2_ui = (const float*)d_in[9];
  const float* b2_ui  = (const float*)d_in[10];
  const float* Wl2_iu = (const float*)d_in[11];
  const float* Wr2_iu = (const float*)d_in[12];
  const float* b2_iu  = (const float*)d_in[13];
  const int* src_u = (const int*)d_in[14];
  const int* dst_i = (const int*)d_in[15];
  const int* label_src = (const int*)d_in[16];
  const int* label_dst = (const int*)d_in[17];

  const int nU = in_sizes[0] / D_IN;
  const int nI = in_sizes[1] / D_IN;
  const int E  = in_sizes[14];
  const int L  = in_sizes[16];
  const int nTot = nI + nU;
  float* out = (float*)d_out;

  char* ws = (char*)d_ws;
  size_t off = 0;
  auto alloc = [&](size_t bytes) -> void* {
    void* p = ws + off;
    off = (off + bytes + 255) & ~(size_t)255;
    return p;
  };
  u16* xU_bf  = (u16*)alloc((size_t)nU * 128 * 2);
  u16* xI_bf  = (u16*)alloc((size_t)nI * 128 * 2);
  u16* wt_l1ui = (u16*)alloc(32768 * 2);
  u16* wt_r1ui = (u16*)alloc(32768 * 2);
  u16* wt_l1iu = (u16*)alloc(32768 * 2);
  u16* wt_r1iu = (u16*)alloc(32768 * 2);
  u16* wt2I    = (u16*)alloc(65536 * 2);   // [tI|pI]: (Wl2_iu | Wr2_ui)^T
  u16* wt2U    = (u16*)alloc(65536 * 2);   // [tU|pU]: (Wl2_ui | Wr2_iu)^T
  u16* agg1I = (u16*)alloc((size_t)nI * 128 * 2);
  u16* agg1U = (u16*)alloc((size_t)nU * 128 * 2);
  u16* hI    = (u16*)alloc((size_t)nI * 256 * 2);
  u16* hU    = (u16*)alloc((size_t)nU * 256 * 2);
  u16* tpI   = (u16*)alloc((size_t)nI * 256 * 2);  // cols 0-127: tI, 128-255: pI
  u16* tpU   = (u16*)alloc((size_t)nU * 256 * 2);
  u16* zI    = (u16*)alloc((size_t)nI * 128 * 2);
  u16* zU    = (u16*)alloc((size_t)nU * 128 * 2);
  int* cnt    = (int*)alloc((size_t)nTot * 4);
  int* pre    = (int*)alloc((size_t)nTot * 4);
  int* bsum   = (int*)alloc(1024 * 4);
  int* rp     = (int*)alloc((size_t)(nTot + 1) * 4);
  int* cursor = (int*)alloc((size_t)nTot * 4);
  int* col    = (int*)alloc((size_t)E * 2 * 4);
  (void)ws_size; (void)n_in; (void)out_size;

  // --- CSR build (fused both directions, hierarchical scan) ---
  hipMemsetAsync(cnt, 0, (size_t)nTot * 4, stream);
  int eb = (E + 255) / 256;
  count_edges_kernel<<<eb, 256, 0, stream>>>(src_u, dst_i, cnt, nI, E);
  int nb = (nTot + 2047) / 2048;
  scan_block_kernel<<<nb, 256, 0, stream>>>(cnt, pre, bsum, nTot);
  scan_sums_kernel<<<1, 1024, 0, stream>>>(bsum, nb);
  scan_add_kernel<<<(nTot + 1 + 255) / 256, 256, 0, stream>>>(
      pre, bsum, rp, cursor, nTot, 2 * E);
  int half = (E + 1) / 2;
  fill_edges_kernel<<<(half + 255) / 256, 256, 0, stream>>>(
      src_u, dst_i, cursor, col, nI, E);
  const int* rpI = rp;
  const int* rpU = rp + nI;

  // --- Convert features + weights to bf16 ---
  f2bf_kernel<<<2048, 256, 0, stream>>>(x_user, xU_bf, nU * 128 / 4);
  f2bf_kernel<<<1250, 256, 0, stream>>>(x_item, xI_bf, nI * 128 / 4);
  wtrans1_kernel<<<dim3(128, 4), 256, 0, stream>>>(
      Wl1_ui, Wr1_ui, Wl1_iu, Wr1_iu, wt_l1ui, wt_r1ui, wt_l1iu, wt_r1iu);
  wtrans2_kernel<<<dim3(256, 2), 256, 0, stream>>>(
      Wl2_iu, Wr2_ui, Wl2_ui, Wr2_iu, wt2I, wt2U);

  // --- Layer 1: agg(128-dim) then dual GEMM (+bias, +relu) ---
  agg_mean_kernel<<<(nI * 64 + 255) / 256, 256, 0, stream>>>(xU_bf, rpI, col, agg1I, nI);
  agg_mean_kernel<<<(nU * 64 + 255) / 256, 256, 0, stream>>>(xI_bf, rpU, col, agg1U, nU);
  gemm_mfma_kernel<128, 256, true, true, true>
      <<<dim3((nI + 127) / 128, 2), 256, 0, stream>>>(
      agg1I, wt_l1ui, xI_bf, wt_r1ui, b1_ui, hI, nI);
  gemm_mfma_kernel<128, 256, true, true, true>
      <<<dim3((nU + 127) / 128, 2), 256, 0, stream>>>(
      agg1U, wt_l1iu, xU_bf, wt_r1iu, b1_iu, hU, nU);

  // --- Layer 2: fused [t|p] GEMM per side, then agg+z epilogue ---
  gemm_mfma_kernel<256, 256, false, false, false>
      <<<dim3((nI + 127) / 128, 2), 256, 0, stream>>>(
      hI, wt2I, nullptr, nullptr, nullptr, tpI, nI);
  gemm_mfma_kernel<256, 256, false, false, false>
      <<<dim3((nU + 127) / 128, 2), 256, 0, stream>>>(
      hU, wt2U, nullptr, nullptr, nullptr, tpU, nU);
  // zI = mean over item's users of tU + pI + b2_ui
  agg_z_kernel<<<(nI * 64 + 255) / 256, 256, 0, stream>>>(
      tpU, tpI, b2_ui, rpI, col, zI, nI);
  // zU = mean over user's items of tI + pU + b2_iu
  agg_z_kernel<<<(nU * 64 + 255) / 256, 256, 0, stream>>>(
      tpI, tpU, b2_iu, rpU, col, zU, nU);

  // --- Decode ---
  decode_kernel<<<((size_t)L * 16 + 255) / 256, 256, 0, stream>>>(
      zU, zI, label_src, label_dst, out, L);
}

// Round 12
// 357.010 us; speedup vs baseline: 2.2240x; 1.0508x over previous
//
#include <hip/hip_runtime.h>
#include <hip/hip_bf16.h>

#define D_IN  128
#define D_HID 256
#define D_OUT 128

typedef unsigned short u16;
typedef __attribute__((ext_vector_type(8))) __bf16 bf16x8;
typedef __attribute__((ext_vector_type(4))) float f32x4;

__device__ inline u16 f2bf(float x) {
  union { float f; unsigned u; } c; c.f = x;
  unsigned r = (c.u + 0x7fff + ((c.u >> 16) & 1)) >> 16;
  return (u16)r;
}
__device__ inline float bf2f(u16 u) {
  union { unsigned u; float f; } c; c.u = (unsigned)u << 16; return c.f;
}
__device__ inline float dot2bf(unsigned x, unsigned y) {
  union { unsigned u; float f; } a, b;
  a.u = x << 16; b.u = y << 16;
  float r = a.f * b.f;
  a.u = x & 0xffff0000u; b.u = y & 0xffff0000u;
  return r + a.f * b.f;
}

// ---------------------------------------------------------------------------
// CSR construction: both directions in ONE cnt/rowptr/col set.
//   [0..nI)      = item nodes (dst side),  col slots [0,E)
//   [nI..nI+nU)  = user nodes (src side),  col slots [E,2E)
// ---------------------------------------------------------------------------
__global__ __launch_bounds__(256) void count_edges_kernel(
    const int* __restrict__ src, const int* __restrict__ dst,
    int* __restrict__ cnt, int nI, int E)
{
  int e = blockIdx.x * 256 + threadIdx.x;
  if (e < E) {
    atomicAdd(&cnt[dst[e]], 1);
    atomicAdd(&cnt[nI + src[e]], 1);
  }
}

__global__ __launch_bounds__(256) void scan_block_kernel(
    const int* __restrict__ cnt, int* __restrict__ pre,
    int* __restrict__ bsum, int n)
{
  __shared__ int wsum[4];
  const int tid = threadIdx.x, lane = tid & 63, wid = tid >> 6;
  const int i0 = blockIdx.x * 2048 + tid * 8;
  int v[8], p[8], s = 0;
  #pragma unroll
  for (int j = 0; j < 8; ++j) {
    int i = i0 + j;
    v[j] = (i < n) ? cnt[i] : 0;
    p[j] = s; s += v[j];
  }
  int ws = s;
  #pragma unroll
  for (int off = 1; off < 64; off <<= 1) {
    int t = __shfl_up(ws, off);
    if (lane >= off) ws += t;
  }
  if (lane == 63) wsum[wid] = ws;
  __syncthreads();
  int woff = 0;
  #pragma unroll
  for (int w = 0; w < 4; ++w)
    if (w < wid) woff += wsum[w];
  int texcl = woff + ws - s;
  #pragma unroll
  for (int j = 0; j < 8; ++j) {
    int i = i0 + j;
    if (i < n) pre[i] = texcl + p[j];
  }
  if (tid == 255) bsum[blockIdx.x] = woff + ws;
}

__global__ __launch_bounds__(1024) void scan_sums_kernel(
    int* __restrict__ bsum, int nb)
{
  __shared__ int wsum[16];
  const int tid = threadIdx.x, lane = tid & 63, wid = tid >> 6;
  int v = (tid < nb) ? bsum[tid] : 0;
  int ws = v;
  #pragma unroll
  for (int off = 1; off < 64; off <<= 1) {
    int t = __shfl_up(ws, off);
    if (lane >= off) ws += t;
  }
  if (lane == 63) wsum[wid] = ws;
  __syncthreads();
  int woff = 0;
  #pragma unroll
  for (int w = 0; w < 16; ++w)
    if (w < wid) woff += wsum[w];
  if (tid < nb) bsum[tid] = woff + ws - v;
}

__global__ __launch_bounds__(256) void scan_add_kernel(
    const int* __restrict__ pre, const int* __restrict__ bsum,
    int* __restrict__ rowptr, int* __restrict__ cursor, int n, int total)
{
  int i = blockIdx.x * 256 + threadIdx.x;
  if (i < n) {
    int v = pre[i] + bsum[i >> 11];
    rowptr[i] = v;
    cursor[i] = v;
  } else if (i == n) {
    rowptr[n] = total;
  }
}

// Fill: 2 edges/thread, NORMAL stores (NT made it worse — round 7).
__global__ __launch_bounds__(256) void fill_edges_kernel(
    const int* __restrict__ src, const int* __restrict__ dst,
    int* __restrict__ cursor, int* __restrict__ col, int nI, int E)
{
  int i = blockIdx.x * 256 + threadIdx.x;
  int half = (E + 1) >> 1;
  if (i >= half) return;
  int e2 = i + half;
  bool v2 = e2 < E;
  int s1 = src[i], d1 = dst[i];
  int s2 = v2 ? src[e2] : 0, d2 = v2 ? dst[e2] : 0;
  int p1 = atomicAdd(&cursor[d1], 1);
  int p2 = v2 ? atomicAdd(&cursor[d2], 1) : 0;
  int q1 = atomicAdd(&cursor[nI + s1], 1);
  int q2 = v2 ? atomicAdd(&cursor[nI + s2], 1) : 0;
  col[p1] = s1;
  col[q1] = d1;
  if (v2) {
    col[p2] = s2;
    col[q2] = d2;
  }
}

// Fused fp32 -> bf16 of both feature arrays.
__global__ __launch_bounds__(256) void f2bf2_kernel(
    const float* __restrict__ a, u16* __restrict__ oa, int n4a,
    const float* __restrict__ b, u16* __restrict__ ob, int n4b)
{
  int stride = gridDim.x * 256;
  int tot = n4a + n4b;
  for (int i = blockIdx.x * 256 + threadIdx.x; i < tot; i += stride) {
    const float* in; u16* out; int j;
    if (i < n4a) { in = a; out = oa; j = i; }
    else         { in = b; out = ob; j = i - n4a; }
    float4 v = ((const float4*)in)[j];
    ushort4 r;
    r.x = f2bf(v.x); r.y = f2bf(v.y); r.z = f2bf(v.z); r.w = f2bf(v.w);
    ((ushort4*)out)[j] = r;
  }
}

// All weight conversions in one dispatch. y<4: L1 transpose; y=4,5: L2 combined.
__global__ __launch_bounds__(256) void wtrans_all_kernel(
    const float* __restrict__ l1a, const float* __restrict__ l1b,
    const float* __restrict__ l1c, const float* __restrict__ l1d,
    u16* __restrict__ o1a, u16* __restrict__ o1b,
    u16* __restrict__ o1c, u16* __restrict__ o1d,
    const float* __restrict__ Wt0, const float* __restrict__ Wp0,
    const float* __restrict__ Wt1, const float* __restrict__ Wp1,
    u16* __restrict__ o2a, u16* __restrict__ o2b)
{
  int y = blockIdx.y;
  int gid = blockIdx.x * 256 + threadIdx.x;
  if (y < 4) {
    if (gid >= 256 * 128) return;
    const float* in = (y == 0) ? l1a : (y == 1) ? l1b : (y == 2) ? l1c : l1d;
    u16* out = (y == 0) ? o1a : (y == 1) ? o1b : (y == 2) ? o1c : o1d;
    int n = gid >> 7, k = gid & 127;
    out[gid] = f2bf(in[(size_t)k * 256 + n]);
  } else {
    if (gid >= 256 * 256) return;
    const float* Wt = (y == 5) ? Wt1 : Wt0;
    const float* Wp = (y == 5) ? Wp1 : Wp0;
    u16* out = (y == 5) ? o2b : o2a;
    int n = gid >> 8, k = gid & 255;
    float v = (n < 128) ? Wt[(size_t)k * 128 + n] : Wp[(size_t)k * 128 + (n - 128)];
    out[gid] = f2bf(v);
  }
}

// Fused layer-1 mean aggregation over ALL nTot nodes; 8 loads in flight.
__global__ __launch_bounds__(256) void agg_mean_all_kernel(
    const u16* __restrict__ xU, const u16* __restrict__ xI,
    const int* __restrict__ rp, const int* __restrict__ col,
    u16* __restrict__ aggI, u16* __restrict__ aggU, int nI, int nTot)
{
  int gid = blockIdx.x * 256 + threadIdx.x;
  int node = gid >> 6, lane = gid & 63;
  if (node >= nTot) return;
  const u16* x = (node < nI) ? xU : xI;
  u16* outrow = (node < nI) ? (aggI + (size_t)node * 128)
                            : (aggU + (size_t)(node - nI) * 128);
  int beg = rp[node], end = rp[node + 1];
  int deg = end - beg;
  float sc = 1.0f / fmaxf((float)deg, 1.0f);
  float a0[8], a1[8];
  #pragma unroll
  for (int t = 0; t < 8; ++t) { a0[t] = 0.f; a1[t] = 0.f; }
  if (deg <= 64) {
    int cidx = (lane < deg) ? col[beg + lane] : 0;
    int dm1 = deg - 1;
    for (int j = 0; j < deg; j += 8) {
      #pragma unroll
      for (int t = 0; t < 8; ++t) {
        int idx = __shfl(cidx, min(j + t, dm1));
        ushort2 v = *(const ushort2*)(x + (size_t)idx * 128 + lane * 2);
        float m = (j + t < deg) ? 1.f : 0.f;
        a0[t] += m * bf2f(v.x);
        a1[t] += m * bf2f(v.y);
      }
    }
  } else {
    for (int e = beg; e < end; ++e) {
      int s = col[e];
      ushort2 v = *(const ushort2*)(x + (size_t)s * 128 + lane * 2);
      a0[0] += bf2f(v.x); a1[0] += bf2f(v.y);
    }
  }
  float r0 = ((a0[0] + a0[1]) + (a0[2] + a0[3])) + ((a0[4] + a0[5]) + (a0[6] + a0[7]));
  float r1 = ((a1[0] + a1[1]) + (a1[2] + a1[3])) + ((a1[4] + a1[5]) + (a1[6] + a1[7]));
  ushort2 r; r.x = f2bf(r0 * sc); r.y = f2bf(r1 * sc);
  *(ushort2*)(outrow + lane * 2) = r;
}

// Fused layer-2 agg + z epilogue over ALL nTot nodes.
__global__ __launch_bounds__(256) void agg_z_all_kernel(
    const u16* __restrict__ tpI, const u16* __restrict__ tpU,
    const float* __restrict__ bI, const float* __restrict__ bU,
    const int* __restrict__ rp, const int* __restrict__ col,
    u16* __restrict__ zI, u16* __restrict__ zU, int nI, int nTot)
{
  int gid = blockIdx.x * 256 + threadIdx.x;
  int node = gid >> 6, lane = gid & 63;
  if (node >= nTot) return;
  bool isI = node < nI;
  const u16* t_src = isI ? tpU : tpI;
  const u16* p_self = isI ? (tpI + (size_t)node * 256)
                          : (tpU + (size_t)(node - nI) * 256);
  const float* bias = isI ? bI : bU;
  u16* zrow = isI ? (zI + (size_t)node * 128)
                  : (zU + (size_t)(node - nI) * 128);
  int beg = rp[node], end = rp[node + 1];
  int deg = end - beg;
  float sc = 1.0f / fmaxf((float)deg, 1.0f);
  float a0[8], a1[8];
  #pragma unroll
  for (int t = 0; t < 8; ++t) { a0[t] = 0.f; a1[t] = 0.f; }
  if (deg <= 64) {
    int cidx = (lane < deg) ? col[beg + lane] : 0;
    int dm1 = deg - 1;
    for (int j = 0; j < deg; j += 8) {
      #pragma unroll
      for (int t = 0; t < 8; ++t) {
        int idx = __shfl(cidx, min(j + t, dm1));
        ushort2 v = *(const ushort2*)(t_src + (size_t)idx * 256 + lane * 2);
        float m = (j + t < deg) ? 1.f : 0.f;
        a0[t] += m * bf2f(v.x);
        a1[t] += m * bf2f(v.y);
      }
    }
  } else {
    for (int e = beg; e < end; ++e) {
      int s = col[e];
      ushort2 v = *(const ushort2*)(t_src + (size_t)s * 256 + lane * 2);
      a0[0] += bf2f(v.x); a1[0] += bf2f(v.y);
    }
  }
  float r0 = ((a0[0] + a0[1]) + (a0[2] + a0[3])) + ((a0[4] + a0[5]) + (a0[6] + a0[7]));
  float r1 = ((a1[0] + a1[1]) + (a1[2] + a1[3])) + ((a1[4] + a1[5]) + (a1[6] + a1[7]));
  ushort2 pv = *(const ushort2*)(p_self + 128 + lane * 2);
  float2 bv = *(const float2*)(bias + lane * 2);
  ushort2 r;
  r.x = f2bf(r0 * sc + bf2f(pv.x) + bv.x);
  r.y = f2bf(r1 * sc + bf2f(pv.y) + bv.y);
  *(ushort2*)(zrow + lane * 2) = r;
}

// GEMM via bf16 MFMA, TWO problem instances per dispatch (side = block range).
template <int K, int N, bool DUAL, bool RELU, bool HAS_BIAS>
__global__ __launch_bounds__(256) void gemm_mfma2_kernel(
    const u16* __restrict__ A1a, const u16* __restrict__ W1a,
    const u16* __restrict__ A2a, const u16* __restrict__ W2a,
    const float* __restrict__ ba, u16* __restrict__ Ca, int Ma, int nbA,
    const u16* __restrict__ A1b, const u16* __restrict__ W1b,
    const u16* __restrict__ A2b, const u16* __restrict__ W2b,
    const float* __restrict__ bb, u16* __restrict__ Cb, int Mb)
{
  constexpr int BK = 64;
  constexpr int LDT = 72;
  __shared__ u16 As[128 * LDT];
  __shared__ u16 Ws[128 * LDT];
  const int tid = threadIdx.x;
  const int lane = tid & 63, wid = tid >> 6;
  const int wr = wid >> 1, wc = wid & 1;
  const bool sb = (int)blockIdx.x >= nbA;
  const u16* A1 = sb ? A1b : A1a;
  const u16* W1 = sb ? W1b : W1a;
  const u16* A2 = sb ? A2b : A2a;
  const u16* W2 = sb ? W2b : W2a;
  const float* bias = sb ? bb : ba;
  u16* Cout = sb ? Cb : Ca;
  const int M = sb ? Mb : Ma;
  const int m0 = (sb ? blockIdx.x - nbA : blockIdx.x) * 128;
  const int n0 = blockIdx.y * 128;
  const int l15 = lane & 15, lg = lane >> 4;

  f32x4 acc[4][4];
  #pragma unroll
  for (int mi = 0; mi < 4; ++mi)
    #pragma unroll
    for (int ni = 0; ni < 4; ++ni) acc[mi][ni] = (f32x4)0.f;

  constexpr int HC = K / BK;
  constexpr int NST = (DUAL ? 2 : 1) * HC;
  for (int st = 0; st < NST; ++st) {
    const u16* Ap; const u16* Wp; int kk;
    if (!DUAL || st < HC) { Ap = A1; Wp = W1; kk = st * BK; }
    else                  { Ap = A2; Wp = W2; kk = (st - HC) * BK; }

    #pragma unroll
    for (int p = 0; p < 4; ++p) {
      int s = tid + p * 256;
      int r = s >> 3, sl = s & 7;
      int grow = m0 + r;
      uint4 v = {0u, 0u, 0u, 0u};
      if (grow < M) v = *(const uint4*)(Ap + (size_t)grow * K + kk + sl * 8);
      *(uint4*)(&As[r * LDT + sl * 8]) = v;
    }
    #pragma unroll
    for (int p = 0; p < 4; ++p) {
      int s = tid + p * 256;
      int r = s >> 3, sl = s & 7;
      *(uint4*)(&Ws[r * LDT + sl * 8]) =
          *(const uint4*)(Wp + (size_t)(n0 + r) * K + kk + sl * 8);
    }
    __syncthreads();

    #pragma unroll
    for (int kh = 0; kh < 2; ++kh) {
      bf16x8 af[4], bf[4];
      #pragma unroll
      for (int mi = 0; mi < 4; ++mi)
        af[mi] = *(const bf16x8*)(&As[(wr * 64 + mi * 16 + l15) * LDT + kh * 32 + lg * 8]);
      #pragma unroll
      for (int ni = 0; ni < 4; ++ni)
        bf[ni] = *(const bf16x8*)(&Ws[(wc * 64 + ni * 16 + l15) * LDT + kh * 32 + lg * 8]);
      #pragma unroll
      for (int mi = 0; mi < 4; ++mi)
        #pragma unroll
        for (int ni = 0; ni < 4; ++ni)
          acc[mi][ni] = __builtin_amdgcn_mfma_f32_16x16x32_bf16(
              af[mi], bf[ni], acc[mi][ni], 0, 0, 0);
    }
    __syncthreads();
  }

  #pragma unroll
  for (int ni = 0; ni < 4; ++ni) {
    int c = n0 + wc * 64 + ni * 16 + l15;
    float bv = HAS_BIAS ? bias[c] : 0.f;
    #pragma unroll
    for (int mi = 0; mi < 4; ++mi) {
      int rowb = m0 + wr * 64 + mi * 16 + lg * 4;
      #pragma unroll
      for (int r = 0; r < 4; ++r) {
        int row = rowb + r;
        if (row < M) {
          float v = acc[mi][ni][r] + bv;
          if (RELU) v = fmaxf(v, 0.f);
          Cout[(size_t)row * N + c] = f2bf(v);
        }
      }
    }
  }
}

// Decode over bf16 z.
__global__ __launch_bounds__(256) void decode_kernel(
    const u16* __restrict__ zu, const u16* __restrict__ zi,
    const int* __restrict__ ls, const int* __restrict__ ld,
    float* __restrict__ out, int L)
{
  int gid = blockIdx.x * 256 + threadIdx.x;
  int li = gid >> 4, lane = gid & 15;
  if (li >= L) return;
  const uint4* pu = (const uint4*)(zu + (size_t)ls[li] * 128);
  const uint4* pv = (const uint4*)(zi + (size_t)ld[li] * 128);
  uint4 a = pu[lane], b = pv[lane];
  float s = dot2bf(a.x, b.x) + dot2bf(a.y, b.y)
          + dot2bf(a.z, b.z) + dot2bf(a.w, b.w);
  #pragma unroll
  for (int m = 8; m >= 1; m >>= 1) s += __shfl_xor(s, m);
  if (lane == 0) {
    out[(size_t)L + li] = s;
    out[li] = -s;
  }
}

// ---------------------------------------------------------------------------
extern "C" void kernel_launch(void* const* d_in, const int* in_sizes, int n_in,
                              void* d_out, int out_size, void* d_ws, size_t ws_size,
                              hipStream_t stream)
{
  const float* x_user = (const float*)d_in[0];
  const float* x_item = (const float*)d_in[1];
  const float* Wl1_ui = (const float*)d_in[2];
  const float* Wr1_ui = (const float*)d_in[3];
  const float* b1_ui  = (const float*)d_in[4];
  const float* Wl1_iu = (const float*)d_in[5];
  const float* Wr1_iu = (const float*)d_in[6];
  const float* b1_iu  = (const float*)d_in[7];
  const float* Wl2_ui = (const float*)d_in[8];
  const float* Wr2_ui = (const float*)d_in[9];
  const float* b2_ui  = (const float*)d_in[10];
  const float* Wl2_iu = (const float*)d_in[11];
  const float* Wr2_iu = (const float*)d_in[12];
  const float* b2_iu  = (const float*)d_in[13];
  const int* src_u = (const int*)d_in[14];
  const int* dst_i = (const int*)d_in[15];
  const int* label_src = (const int*)d_in[16];
  const int* label_dst = (const int*)d_in[17];

  const int nU = in_sizes[0] / D_IN;
  const int nI = in_sizes[1] / D_IN;
  const int E  = in_sizes[14];
  const int L  = in_sizes[16];
  const int nTot = nI + nU;
  float* out = (float*)d_out;

  char* ws = (char*)d_ws;
  size_t off = 0;
  auto alloc = [&](size_t bytes) -> void* {
    void* p = ws + off;
    off = (off + bytes + 255) & ~(size_t)255;
    return p;
  };
  u16* xU_bf  = (u16*)alloc((size_t)nU * 128 * 2);
  u16* xI_bf  = (u16*)alloc((size_t)nI * 128 * 2);
  u16* wt_l1ui = (u16*)alloc(32768 * 2);
  u16* wt_r1ui = (u16*)alloc(32768 * 2);
  u16* wt_l1iu = (u16*)alloc(32768 * 2);
  u16* wt_r1iu = (u16*)alloc(32768 * 2);
  u16* wt2I    = (u16*)alloc(65536 * 2);   // [tI|pI]: (Wl2_iu | Wr2_ui)^T
  u16* wt2U    = (u16*)alloc(65536 * 2);   // [tU|pU]: (Wl2_ui | Wr2_iu)^T
  u16* agg1I = (u16*)alloc((size_t)nI * 128 * 2);
  u16* agg1U = (u16*)alloc((size_t)nU * 128 * 2);
  u16* hI    = (u16*)alloc((size_t)nI * 256 * 2);
  u16* hU    = (u16*)alloc((size_t)nU * 256 * 2);
  u16* tpI   = (u16*)alloc((size_t)nI * 256 * 2);  // cols 0-127: t, 128-255: p
  u16* tpU   = (u16*)alloc((size_t)nU * 256 * 2);
  u16* zI    = (u16*)alloc((size_t)nI * 128 * 2);
  u16* zU    = (u16*)alloc((size_t)nU * 128 * 2);
  int* cnt    = (int*)alloc((size_t)nTot * 4);
  int* pre    = (int*)alloc((size_t)nTot * 4);
  int* bsum   = (int*)alloc(1024 * 4);
  int* rp     = (int*)alloc((size_t)(nTot + 1) * 4);
  int* cursor = (int*)alloc((size_t)nTot * 4);
  int* col    = (int*)alloc((size_t)E * 2 * 4);
  (void)ws_size; (void)n_in; (void)out_size;

  // --- CSR build ---
  hipMemsetAsync(cnt, 0, (size_t)nTot * 4, stream);
  int eb = (E + 255) / 256;
  count_edges_kernel<<<eb, 256, 0, stream>>>(src_u, dst_i, cnt, nI, E);
  int nb = (nTot + 2047) / 2048;
  scan_block_kernel<<<nb, 256, 0, stream>>>(cnt, pre, bsum, nTot);
  scan_sums_kernel<<<1, 1024, 0, stream>>>(bsum, nb);
  scan_add_kernel<<<(nTot + 1 + 255) / 256, 256, 0, stream>>>(
      pre, bsum, rp, cursor, nTot, 2 * E);
  int half = (E + 1) / 2;
  fill_edges_kernel<<<(half + 255) / 256, 256, 0, stream>>>(
      src_u, dst_i, cursor, col, nI, E);

  // --- Conversions (one dispatch each) ---
  f2bf2_kernel<<<2048, 256, 0, stream>>>(
      x_user, xU_bf, nU * 128 / 4, x_item, xI_bf, nI * 128 / 4);
  wtrans_all_kernel<<<dim3(256, 6), 256, 0, stream>>>(
      Wl1_ui, Wr1_ui, Wl1_iu, Wr1_iu, wt_l1ui, wt_r1ui, wt_l1iu, wt_r1iu,
      Wl2_iu, Wr2_ui, Wl2_ui, Wr2_iu, wt2I, wt2U);

  // --- Layer 1: fused agg (all nodes) + fused dual-GEMM dispatch ---
  agg_mean_all_kernel<<<(nTot * 64 + 255) / 256, 256, 0, stream>>>(
      xU_bf, xI_bf, rp, col, agg1I, agg1U, nI, nTot);
  int nbI = (nI + 127) / 128, nbU = (nU + 127) / 128;
  gemm_mfma2_kernel<128, 256, true, true, true>
      <<<dim3(nbI + nbU, 2), 256, 0, stream>>>(
      agg1I, wt_l1ui, xI_bf, wt_r1ui, b1_ui, hI, nI, nbI,
      agg1U, wt_l1iu, xU_bf, wt_r1iu, b1_iu, hU, nU);

  // --- Layer 2: fused [t|p] GEMM (both sides) + fused agg+z ---
  gemm_mfma2_kernel<256, 256, false, false, false>
      <<<dim3(nbI + nbU, 2), 256, 0, stream>>>(
      hI, wt2I, nullptr, nullptr, nullptr, tpI, nI, nbI,
      hU, wt2U, nullptr, nullptr, nullptr, tpU, nU);
  agg_z_all_kernel<<<(nTot * 64 + 255) / 256, 256, 0, stream>>>(
      tpI, tpU, b2_ui, b2_iu, rp, col, zI, zU, nI, nTot);

  // --- Decode ---
  decode_kernel<<<((size_t)L * 16 + 255) / 256, 256, 0, stream>>>(
      zU, zI, label_src, label_dst, out, L);
}

// Round 14
// 346.294 us; speedup vs baseline: 2.2929x; 1.0309x over previous
//
#include <hip/hip_runtime.h>
#include <hip/hip_bf16.h>

#define D_IN  128
#define D_HID 256
#define D_OUT 128

typedef unsigned short u16;
typedef __attribute__((ext_vector_type(8))) __bf16 bf16x8;
typedef __attribute__((ext_vector_type(4))) float f32x4;

__device__ inline u16 f2bf(float x) {
  union { float f; unsigned u; } c; c.f = x;
  unsigned r = (c.u + 0x7fff + ((c.u >> 16) & 1)) >> 16;
  return (u16)r;
}
__device__ inline float bf2f(u16 u) {
  union { unsigned u; float f; } c; c.u = (unsigned)u << 16; return c.f;
}
__device__ inline float dot2bf(unsigned x, unsigned y) {
  union { unsigned u; float f; } a, b;
  a.u = x << 16; b.u = y << 16;
  float r = a.f * b.f;
  a.u = x & 0xffff0000u; b.u = y & 0xffff0000u;
  return r + a.f * b.f;
}

// ---------------------------------------------------------------------------
// CSR construction: both directions in ONE cnt/rowptr/col set.
//   [0..nI)      = item nodes (dst side),  col slots [0,E)
//   [nI..nI+nU)  = user nodes (src side),  col slots [E,2E)
// ---------------------------------------------------------------------------
__global__ __launch_bounds__(256) void count_edges_kernel(
    const int* __restrict__ src, const int* __restrict__ dst,
    int* __restrict__ cnt, int nI, int E)
{
  int e = blockIdx.x * 256 + threadIdx.x;
  if (e < E) {
    atomicAdd(&cnt[dst[e]], 1);
    atomicAdd(&cnt[nI + src[e]], 1);
  }
}

__global__ __launch_bounds__(256) void scan_block_kernel(
    const int* __restrict__ cnt, int* __restrict__ pre,
    int* __restrict__ bsum, int n)
{
  __shared__ int wsum[4];
  const int tid = threadIdx.x, lane = tid & 63, wid = tid >> 6;
  const int i0 = blockIdx.x * 2048 + tid * 8;
  int v[8], p[8], s = 0;
  #pragma unroll
  for (int j = 0; j < 8; ++j) {
    int i = i0 + j;
    v[j] = (i < n) ? cnt[i] : 0;
    p[j] = s; s += v[j];
  }
  int ws = s;
  #pragma unroll
  for (int off = 1; off < 64; off <<= 1) {
    int t = __shfl_up(ws, off);
    if (lane >= off) ws += t;
  }
  if (lane == 63) wsum[wid] = ws;
  __syncthreads();
  int woff = 0;
  #pragma unroll
  for (int w = 0; w < 4; ++w)
    if (w < wid) woff += wsum[w];
  int texcl = woff + ws - s;
  #pragma unroll
  for (int j = 0; j < 8; ++j) {
    int i = i0 + j;
    if (i < n) pre[i] = texcl + p[j];
  }
  if (tid == 255) bsum[blockIdx.x] = woff + ws;
}

__global__ __launch_bounds__(1024) void scan_sums_kernel(
    int* __restrict__ bsum, int nb)
{
  __shared__ int wsum[16];
  const int tid = threadIdx.x, lane = tid & 63, wid = tid >> 6;
  int v = (tid < nb) ? bsum[tid] : 0;
  int ws = v;
  #pragma unroll
  for (int off = 1; off < 64; off <<= 1) {
    int t = __shfl_up(ws, off);
    if (lane >= off) ws += t;
  }
  if (lane == 63) wsum[wid] = ws;
  __syncthreads();
  int woff = 0;
  #pragma unroll
  for (int w = 0; w < 16; ++w)
    if (w < wid) woff += wsum[w];
  if (tid < nb) bsum[tid] = woff + ws - v;
}

__global__ __launch_bounds__(256) void scan_add_kernel(
    const int* __restrict__ pre, const int* __restrict__ bsum,
    int* __restrict__ rowptr, int* __restrict__ cursor, int n, int total)
{
  int i = blockIdx.x * 256 + threadIdx.x;
  if (i < n) {
    int v = pre[i] + bsum[i >> 11];
    rowptr[i] = v;
    cursor[i] = v;
  } else if (i == n) {
    rowptr[n] = total;
  }
}

// Fill: 2 edges/thread, NORMAL stores (NT made it worse — round 7).
__global__ __launch_bounds__(256) void fill_edges_kernel(
    const int* __restrict__ src, const int* __restrict__ dst,
    int* __restrict__ cursor, int* __restrict__ col, int nI, int E)
{
  int i = blockIdx.x * 256 + threadIdx.x;
  int half = (E + 1) >> 1;
  if (i >= half) return;
  int e2 = i + half;
  bool v2 = e2 < E;
  int s1 = src[i], d1 = dst[i];
  int s2 = v2 ? src[e2] : 0, d2 = v2 ? dst[e2] : 0;
  int p1 = atomicAdd(&cursor[d1], 1);
  int p2 = v2 ? atomicAdd(&cursor[d2], 1) : 0;
  int q1 = atomicAdd(&cursor[nI + s1], 1);
  int q2 = v2 ? atomicAdd(&cursor[nI + s2], 1) : 0;
  col[p1] = s1;
  col[q1] = d1;
  if (v2) {
    col[p2] = s2;
    col[q2] = d2;
  }
}

// Fused fp32 -> bf16 of both feature arrays.
__global__ __launch_bounds__(256) void f2bf2_kernel(
    const float* __restrict__ a, u16* __restrict__ oa, int n4a,
    const float* __restrict__ b, u16* __restrict__ ob, int n4b)
{
  int stride = gridDim.x * 256;
  int tot = n4a + n4b;
  for (int i = blockIdx.x * 256 + threadIdx.x; i < tot; i += stride) {
    const float* in; u16* out; int j;
    if (i < n4a) { in = a; out = oa; j = i; }
    else         { in = b; out = ob; j = i - n4a; }
    float4 v = ((const float4*)in)[j];
    ushort4 r;
    r.x = f2bf(v.x); r.y = f2bf(v.y); r.z = f2bf(v.z); r.w = f2bf(v.w);
    ((ushort4*)out)[j] = r;
  }
}

// All weight conversions in one dispatch. y<4: L1 transpose; y=4,5: L2 combined.
__global__ __launch_bounds__(256) void wtrans_all_kernel(
    const float* __restrict__ l1a, const float* __restrict__ l1b,
    const float* __restrict__ l1c, const float* __restrict__ l1d,
    u16* __restrict__ o1a, u16* __restrict__ o1b,
    u16* __restrict__ o1c, u16* __restrict__ o1d,
    const float* __restrict__ Wt0, const float* __restrict__ Wp0,
    const float* __restrict__ Wt1, const float* __restrict__ Wp1,
    u16* __restrict__ o2a, u16* __restrict__ o2b)
{
  int y = blockIdx.y;
  int gid = blockIdx.x * 256 + threadIdx.x;
  if (y < 4) {
    if (gid >= 256 * 128) return;
    const float* in = (y == 0) ? l1a : (y == 1) ? l1b : (y == 2) ? l1c : l1d;
    u16* out = (y == 0) ? o1a : (y == 1) ? o1b : (y == 2) ? o1c : o1d;
    int n = gid >> 7, k = gid & 127;
    out[gid] = f2bf(in[(size_t)k * 256 + n]);
  } else {
    if (gid >= 256 * 256) return;
    const float* Wt = (y == 5) ? Wt1 : Wt0;
    const float* Wp = (y == 5) ? Wp1 : Wp0;
    u16* out = (y == 5) ? o2b : o2a;
    int n = gid >> 8, k = gid & 255;
    float v = (n < 128) ? Wt[(size_t)k * 128 + n] : Wp[(size_t)k * 128 + (n - 128)];
    out[gid] = f2bf(v);
  }
}

// Fused layer-1 mean aggregation over ALL nTot nodes; 8 loads in flight.
__global__ __launch_bounds__(256) void agg_mean_all_kernel(
    const u16* __restrict__ xU, const u16* __restrict__ xI,
    const int* __restrict__ rp, const int* __restrict__ col,
    u16* __restrict__ aggI, u16* __restrict__ aggU, int nI, int nTot)
{
  int gid = blockIdx.x * 256 + threadIdx.x;
  int node = gid >> 6, lane = gid & 63;
  if (node >= nTot) return;
  const u16* x = (node < nI) ? xU : xI;
  u16* outrow = (node < nI) ? (aggI + (size_t)node * 128)
                            : (aggU + (size_t)(node - nI) * 128);
  int beg = rp[node], end = rp[node + 1];
  int deg = end - beg;
  float sc = 1.0f / fmaxf((float)deg, 1.0f);
  float a0[8], a1[8];
  #pragma unroll
  for (int t = 0; t < 8; ++t) { a0[t] = 0.f; a1[t] = 0.f; }
  if (deg <= 64) {
    int cidx = (lane < deg) ? col[beg + lane] : 0;
    int dm1 = deg - 1;
    for (int j = 0; j < deg; j += 8) {
      #pragma unroll
      for (int t = 0; t < 8; ++t) {
        int idx = __shfl(cidx, min(j + t, dm1));
        ushort2 v = *(const ushort2*)(x + (size_t)idx * 128 + lane * 2);
        float m = (j + t < deg) ? 1.f : 0.f;
        a0[t] += m * bf2f(v.x);
        a1[t] += m * bf2f(v.y);
      }
    }
  } else {
    for (int e = beg; e < end; ++e) {
      int s = col[e];
      ushort2 v = *(const ushort2*)(x + (size_t)s * 128 + lane * 2);
      a0[0] += bf2f(v.x); a1[0] += bf2f(v.y);
    }
  }
  float r0 = ((a0[0] + a0[1]) + (a0[2] + a0[3])) + ((a0[4] + a0[5]) + (a0[6] + a0[7]));
  float r1 = ((a1[0] + a1[1]) + (a1[2] + a1[3])) + ((a1[4] + a1[5]) + (a1[6] + a1[7]));
  ushort2 r; r.x = f2bf(r0 * sc); r.y = f2bf(r1 * sc);
  *(ushort2*)(outrow + lane * 2) = r;
}

// Fused layer-2 agg + z epilogue over ALL nTot nodes.
__global__ __launch_bounds__(256) void agg_z_all_kernel(
    const u16* __restrict__ tpI, const u16* __restrict__ tpU,
    const float* __restrict__ bI, const float* __restrict__ bU,
    const int* __restrict__ rp, const int* __restrict__ col,
    u16* __restrict__ zI, u16* __restrict__ zU, int nI, int nTot)
{
  int gid = blockIdx.x * 256 + threadIdx.x;
  int node = gid >> 6, lane = gid & 63;
  if (node >= nTot) return;
  bool isI = node < nI;
  const u16* t_src = isI ? tpU : tpI;
  const u16* p_self = isI ? (tpI + (size_t)node * 256)
                          : (tpU + (size_t)(node - nI) * 256);
  const float* bias = isI ? bI : bU;
  u16* zrow = isI ? (zI + (size_t)node * 128)
                  : (zU + (size_t)(node - nI) * 128);
  int beg = rp[node], end = rp[node + 1];
  int deg = end - beg;
  float sc = 1.0f / fmaxf((float)deg, 1.0f);
  float a0[8], a1[8];
  #pragma unroll
  for (int t = 0; t < 8; ++t) { a0[t] = 0.f; a1[t] = 0.f; }
  if (deg <= 64) {
    int cidx = (lane < deg) ? col[beg + lane] : 0;
    int dm1 = deg - 1;
    for (int j = 0; j < deg; j += 8) {
      #pragma unroll
      for (int t = 0; t < 8; ++t) {
        int idx = __shfl(cidx, min(j + t, dm1));
        ushort2 v = *(const ushort2*)(t_src + (size_t)idx * 256 + lane * 2);
        float m = (j + t < deg) ? 1.f : 0.f;
        a0[t] += m * bf2f(v.x);
        a1[t] += m * bf2f(v.y);
      }
    }
  } else {
    for (int e = beg; e < end; ++e) {
      int s = col[e];
      ushort2 v = *(const ushort2*)(t_src + (size_t)s * 256 + lane * 2);
      a0[0] += bf2f(v.x); a1[0] += bf2f(v.y);
    }
  }
  float r0 = ((a0[0] + a0[1]) + (a0[2] + a0[3])) + ((a0[4] + a0[5]) + (a0[6] + a0[7]));
  float r1 = ((a1[0] + a1[1]) + (a1[2] + a1[3])) + ((a1[4] + a1[5]) + (a1[6] + a1[7]));
  ushort2 pv = *(const ushort2*)(p_self + 128 + lane * 2);
  float2 bv = *(const float2*)(bias + lane * 2);
  ushort2 r;
  r.x = f2bf(r0 * sc + bf2f(pv.x) + bv.x);
  r.y = f2bf(r1 * sc + bf2f(pv.y) + bv.y);
  *(ushort2*)(zrow + lane * 2) = r;
}

// ---------------------------------------------------------------------------
// Direct-A GEMM via bf16 MFMA, N=256 fixed, TWO problem instances per
// dispatch. C[M,256] = A1@W1 (+A2@W2 if DUAL) (+bias) (+relu).
// 512 threads = 8 waves (2 row x 4 col), block tile 128x256 (full N -> A read
// ONCE). A-fragments load DIRECT from global (coalesced 64-B lines per row;
// not barrier-gated). Only the 32-KB L2-hot W chunk stages through LDS.
// Epilogue bounces acc through per-wave LDS slices for coalesced uint4 stores
// (round-12 profile: scalar 2-B stores caused 60 MB WRITE for 36 MB of C).
// ---------------------------------------------------------------------------
template <int K, bool DUAL, bool RELU, bool HAS_BIAS>
__global__ __launch_bounds__(512) void gemm_dn_kernel(
    const u16* __restrict__ A1a, const u16* __restrict__ W1a,
    const u16* __restrict__ A2a, const u16* __restrict__ W2a,
    const float* __restrict__ ba, u16* __restrict__ Ca, int Ma, int nbA,
    const u16* __restrict__ A1b, const u16* __restrict__ W1b,
    const u16* __restrict__ A2b, const u16* __restrict__ W2b,
    const float* __restrict__ bb, u16* __restrict__ Cb, int Mb)
{
  constexpr int N = 256;
  constexpr int LDT = 72;               // 144-B padded rows
  __shared__ u16 Ws[256 * LDT];         // 36 KB W chunk; reused as bounce
  const int tid = threadIdx.x;
  const int lane = tid & 63, wid = tid >> 6;
  const int wr = wid >> 2, wc = wid & 3;
  const bool sb = (int)blockIdx.x >= nbA;
  const u16* A1 = sb ? A1b : A1a;
  const u16* W1 = sb ? W1b : W1a;
  const u16* A2 = sb ? A2b : A2a;
  const u16* W2 = sb ? W2b : W2a;
  const float* bias = sb ? bb : ba;
  u16* Cout = sb ? Cb : Ca;
  const int M = sb ? Mb : Ma;
  const int m0 = (sb ? blockIdx.x - nbA : blockIdx.x) * 128;
  const int l15 = lane & 15, lg = lane >> 4;
  const int rowbase = m0 + wr * 64;

  f32x4 acc[4][4];
  #pragma unroll
  for (int mi = 0; mi < 4; ++mi)
    #pragma unroll
    for (int ni = 0; ni < 4; ++ni) acc[mi][ni] = (f32x4)0.f;

  constexpr int HC = K / 64;
  constexpr int NST = (DUAL ? 2 : 1) * HC;
  const int wrow = tid >> 1;            // W staging: 2 threads/row
  const int whf  = (tid & 1) * 32;      // 32-elem half of the 64-k chunk

  for (int st = 0; st < NST; ++st) {
    const u16* Ap; const u16* Wp; int kc;
    if (!DUAL || st < HC) { Ap = A1; Wp = W1; kc = st * 64; }
    else                  { Ap = A2; Wp = W2; kc = (st - HC) * 64; }

    if (st) __syncthreads();            // prev compute done before overwrite
    {
      const u16* src = Wp + (size_t)wrow * K + kc + whf;
      u16* dst = &Ws[wrow * LDT + whf];
      #pragma unroll
      for (int j = 0; j < 4; ++j)
        *(uint4*)(dst + j * 8) = *(const uint4*)(src + j * 8);
    }
    __syncthreads();

    #pragma unroll
    for (int kh = 0; kh < 2; ++kh) {
      bf16x8 af[4], bf[4];
      #pragma unroll
      for (int mi = 0; mi < 4; ++mi) {
        int row = rowbase + mi * 16 + l15;
        uint4 t = {0u, 0u, 0u, 0u};
        if (row < M)
          t = *(const uint4*)(Ap + (size_t)row * K + kc + kh * 32 + lg * 8);
        af[mi] = *(bf16x8*)&t;
      }
      #pragma unroll
      for (int ni = 0; ni < 4; ++ni)
        bf[ni] = *(const bf16x8*)(&Ws[(wc * 64 + ni * 16 + l15) * LDT + kh * 32 + lg * 8]);
      #pragma unroll
      for (int mi = 0; mi < 4; ++mi)
        #pragma unroll
        for (int ni = 0; ni < 4; ++ni)
          acc[mi][ni] = __builtin_amdgcn_mfma_f32_16x16x32_bf16(
              af[mi], bf[ni], acc[mi][ni], 0, 0, 0);
    }
  }
  __syncthreads();                      // compute done; Ws becomes bounce buf

  // Epilogue: per-wave private 16x64 LDS slice -> coalesced uint4 stores.
  u16* slice = &Ws[wid * 16 * LDT];
  float bvs[4];
  #pragma unroll
  for (int ni = 0; ni < 4; ++ni)
    bvs[ni] = HAS_BIAS ? bias[wc * 64 + ni * 16 + l15] : 0.f;
  const int rl = lane >> 2, part = lane & 3;
  #pragma unroll
  for (int mi = 0; mi < 4; ++mi) {
    #pragma unroll
    for (int ni = 0; ni < 4; ++ni) {
      #pragma unroll
      for (int r = 0; r < 4; ++r) {
        float v = acc[mi][ni][r] + bvs[ni];
        if (RELU) v = fmaxf(v, 0.f);
        slice[(lg * 4 + r) * LDT + ni * 16 + l15] = f2bf(v);
      }
    }
    uint4 v0 = *(const uint4*)(slice + rl * LDT + part * 16);
    uint4 v1 = *(const uint4*)(slice + rl * LDT + part * 16 + 8);
    int grow = rowbase + mi * 16 + rl;
    if (grow < M) {
      u16* cp = Cout + (size_t)grow * N + wc * 64 + part * 16;
      *(uint4*)cp = v0;
      *(uint4*)(cp + 8) = v1;
    }
  }
}

// Decode over bf16 z.
__global__ __launch_bounds__(256) void decode_kernel(
    const u16* __restrict__ zu, const u16* __restrict__ zi,
    const int* __restrict__ ls, const int* __restrict__ ld,
    float* __restrict__ out, int L)
{
  int gid = blockIdx.x * 256 + threadIdx.x;
  int li = gid >> 4, lane = gid & 15;
  if (li >= L) return;
  const uint4* pu = (const uint4*)(zu + (size_t)ls[li] * 128);
  const uint4* pv = (const uint4*)(zi + (size_t)ld[li] * 128);
  uint4 a = pu[lane], b = pv[lane];
  float s = dot2bf(a.x, b.x) + dot2bf(a.y, b.y)
          + dot2bf(a.z, b.z) + dot2bf(a.w, b.w);
  #pragma unroll
  for (int m = 8; m >= 1; m >>= 1) s += __shfl_xor(s, m);
  if (lane == 0) {
    out[(size_t)L + li] = s;
    out[li] = -s;
  }
}

// ---------------------------------------------------------------------------
extern "C" void kernel_launch(void* const* d_in, const int* in_sizes, int n_in,
                              void* d_out, int out_size, void* d_ws, size_t ws_size,
                              hipStream_t stream)
{
  const float* x_user = (const float*)d_in[0];
  const float* x_item = (const float*)d_in[1];
  const float* Wl1_ui = (const float*)d_in[2];
  const float* Wr1_ui = (const float*)d_in[3];
  const float* b1_ui  = (const float*)d_in[4];
  const float* Wl1_iu = (const float*)d_in[5];
  const float* Wr1_iu = (const float*)d_in[6];
  const float* b1_iu  = (const float*)d_in[7];
  const float* Wl2_ui = (const float*)d_in[8];
  const float* Wr2_ui = (const float*)d_in[9];
  const float* b2_ui  = (const float*)d_in[10];
  const float* Wl2_iu = (const float*)d_in[11];
  const float* Wr2_iu = (const float*)d_in[12];
  const float* b2_iu  = (const float*)d_in[13];
  const int* src_u = (const int*)d_in[14];
  const int* dst_i = (const int*)d_in[15];
  const int* label_src = (const int*)d_in[16];
  const int* label_dst = (const int*)d_in[17];

  const int nU = in_sizes[0] / D_IN;
  const int nI = in_sizes[1] / D_IN;
  const int E  = in_sizes[14];
  const int L  = in_sizes[16];
  const int nTot = nI + nU;
  float* out = (float*)d_out;

  char* ws = (char*)d_ws;
  size_t off = 0;
  auto alloc = [&](size_t bytes) -> void* {
    void* p = ws + off;
    off = (off + bytes + 255) & ~(size_t)255;
    return p;
  };
  u16* xU_bf  = (u16*)alloc((size_t)nU * 128 * 2);
  u16* xI_bf  = (u16*)alloc((size_t)nI * 128 * 2);
  u16* wt_l1ui = (u16*)alloc(32768 * 2);
  u16* wt_r1ui = (u16*)alloc(32768 * 2);
  u16* wt_l1iu = (u16*)alloc(32768 * 2);
  u16* wt_r1iu = (u16*)alloc(32768 * 2);
  u16* wt2I    = (u16*)alloc(65536 * 2);   // [tI|pI]: (Wl2_iu | Wr2_ui)^T
  u16* wt2U    = (u16*)alloc(65536 * 2);   // [tU|pU]: (Wl2_ui | Wr2_iu)^T
  u16* agg1I = (u16*)alloc((size_t)nI * 128 * 2);
  u16* agg1U = (u16*)alloc((size_t)nU * 128 * 2);
  u16* hI    = (u16*)alloc((size_t)nI * 256 * 2);
  u16* hU    = (u16*)alloc((size_t)nU * 256 * 2);
  u16* tpI   = (u16*)alloc((size_t)nI * 256 * 2);  // cols 0-127: t, 128-255: p
  u16* tpU   = (u16*)alloc((size_t)nU * 256 * 2);
  u16* zI    = (u16*)alloc((size_t)nI * 128 * 2);
  u16* zU    = (u16*)alloc((size_t)nU * 128 * 2);
  int* cnt    = (int*)alloc((size_t)nTot * 4);
  int* pre    = (int*)alloc((size_t)nTot * 4);
  int* bsum   = (int*)alloc(1024 * 4);
  int* rp     = (int*)alloc((size_t)(nTot + 1) * 4);
  int* cursor = (int*)alloc((size_t)nTot * 4);
  int* col    = (int*)alloc((size_t)E * 2 * 4);
  (void)ws_size; (void)n_in; (void)out_size;

  // --- CSR build ---
  hipMemsetAsync(cnt, 0, (size_t)nTot * 4, stream);
  int eb = (E + 255) / 256;
  count_edges_kernel<<<eb, 256, 0, stream>>>(src_u, dst_i, cnt, nI, E);
  int nb = (nTot + 2047) / 2048;
  scan_block_kernel<<<nb, 256, 0, stream>>>(cnt, pre, bsum, nTot);
  scan_sums_kernel<<<1, 1024, 0, stream>>>(bsum, nb);
  scan_add_kernel<<<(nTot + 1 + 255) / 256, 256, 0, stream>>>(
      pre, bsum, rp, cursor, nTot, 2 * E);
  int half = (E + 1) / 2;
  fill_edges_kernel<<<(half + 255) / 256, 256, 0, stream>>>(
      src_u, dst_i, cursor, col, nI, E);

  // --- Conversions (one dispatch each) ---
  f2bf2_kernel<<<2048, 256, 0, stream>>>(
      x_user, xU_bf, nU * 128 / 4, x_item, xI_bf, nI * 128 / 4);
  wtrans_all_kernel<<<dim3(256, 6), 256, 0, stream>>>(
      Wl1_ui, Wr1_ui, Wl1_iu, Wr1_iu, wt_l1ui, wt_r1ui, wt_l1iu, wt_r1iu,
      Wl2_iu, Wr2_ui, Wl2_ui, Wr2_iu, wt2I, wt2U);

  // --- Layer 1: fused agg (all nodes) + fused dual-GEMM dispatch ---
  agg_mean_all_kernel<<<(nTot * 64 + 255) / 256, 256, 0, stream>>>(
      xU_bf, xI_bf, rp, col, agg1I, agg1U, nI, nTot);
  int nbI = (nI + 127) / 128, nbU = (nU + 127) / 128;
  gemm_dn_kernel<128, true, true, true>
      <<<nbI + nbU, 512, 0, stream>>>(
      agg1I, wt_l1ui, xI_bf, wt_r1ui, b1_ui, hI, nI, nbI,
      agg1U, wt_l1iu, xU_bf, wt_r1iu, b1_iu, hU, nU);

  // --- Layer 2: fused [t|p] GEMM (both sides) + fused agg+z ---
  gemm_dn_kernel<256, false, false, false>
      <<<nbI + nbU, 512, 0, stream>>>(
      hI, wt2I, nullptr, nullptr, nullptr, tpI, nI, nbI,
      hU, wt2U, nullptr, nullptr, nullptr, tpU, nU);
  agg_z_all_kernel<<<(nTot * 64 + 255) / 256, 256, 0, stream>>>(
      tpI, tpU, b2_ui, b2_iu, rp, col, zI, zU, nI, nTot);

  // --- Decode ---
  decode_kernel<<<((size_t)L * 16 + 255) / 256, 256, 0, stream>>>(
      zU, zI, label_src, label_dst, out, L);
}